// Round 4
// baseline (5107.189 us; speedup 1.0000x reference)
//
#include <hip/hip_runtime.h>
#include <hip/hip_bf16.h>

typedef __attribute__((ext_vector_type(8))) short s8;
typedef __attribute__((ext_vector_type(4))) float f4;

using bf16 = __hip_bfloat16;

#define MFMA16(a,b,c) __builtin_amdgcn_mfma_f32_16x16x32_bf16((a),(b),(c),0,0,0)

// HW_REG_XCC_ID (id=20), offset 0, width 4  ->  simm16 = id | (off<<6) | ((w-1)<<11)
#define GETREG_XCC_ID (20 | (0 << 6) | (3 << 11))

// ---------------- sizes ----------------
constexpr int SS = 512, BBATCH = 64, HIDN = 512;
constexpr size_t DEC_SZ = (size_t)SS * BBATCH * HIDN;  // 16777216 f32 = 64MiB

// ---------------- ws layout (bytes), total 101 MiB ----------------
constexpr size_t OF_FLAGS = 0;                  // 512*32*4 = 64KiB (one 128B line per step)
constexpr size_t OF_BIAS4 = 65536;              // 2048 f32
constexpr size_t OF_BIASQ = 73728;              // 1536 f32  (ends 79872)
constexpr size_t OF_CLAIM = 81920;              // 1 int (worker-slot counter)
constexpr size_t OF_BTX   = 131072;             // Bt_x [2048][256] bf16 = 1MiB
constexpr size_t OF_BTH   = 1179648;            // Bt_h [2048][512] bf16 = 2MiB
constexpr size_t OF_BTQKV = 3276800;            // Bt_qkv [1536][512] bf16 = 1.5MiB
constexpr size_t OF_YQ    = (size_t)5  << 20;   // 32MiB
constexpr size_t OF_YK    = OF_YQ + ((size_t)32 << 20);
constexpr size_t OF_VT    = OF_YK + ((size_t)32 << 20);   // ends at 101MiB

// d_out scratch offsets (inside 64MiB decoded region; dead before decode writes)
constexpr size_t DOUT_LOUT = 0;                 // lout bf16 [32768][512] = 32MiB
constexpr size_t DOUT_XBF  = (size_t)32 << 20;  // xbf bf16 [32768][256] = 16MiB

// ---------------- helpers ----------------
__device__ inline s8 ldg8(const bf16* p){ return *(const s8*)p; }
__device__ inline short f2bs(float f){ return __builtin_bit_cast(short, __float2bfloat16(f)); }
__device__ inline float sigf(float x){ return 1.f/(1.f + __expf(-x)); }
__device__ inline float tanhf_(float x){ x = fminf(fmaxf(x, -15.f), 15.f); float e = __expf(2.f*x); return (e-1.f)/(e+1.f); }

// ================= K0: pack weights/biases/x, zero flags =================
__global__ void k0_pack(const float* x,
                        const float* Wf,const float* Wi,const float* Wg,const float* Wo,
                        const float* bfv,const float* biv,const float* bgv,const float* bov,
                        const float* Wq,const float* Wk,const float* Wv,
                        const float* bqv,const float* bkv,const float* bvv,
                        bf16* xbf, bf16* btx, bf16* bth, bf16* btqkv,
                        float* bias4, float* biasq, int* flags, int* claim)
{
  const float* WG[4] = {Wf, Wi, Wg, Wo};
  const float* BG[4] = {bfv, biv, bgv, bov};
  const float* WQ[3] = {Wq, Wk, Wv};
  const float* BQ[3] = {bqv, bkv, bvv};
  const long NX   = 8388608;   // 32768*256
  const long NBTH = 1048576;   // 2048*512
  const long NBTQ = 786432;    // 1536*512
  const long NBTX = 524288;    // 2048*256
  const long NF   = 16384;     // 512*32
  const long TOT  = NX + NBTH + NBTQ + NBTX + NF + 2048 + 1536 + 1;
  long stride = (long)gridDim.x * blockDim.x;
  for (long i = (long)blockIdx.x*blockDim.x + threadIdx.x; i < TOT; i += stride){
    if (i < NX){ xbf[i] = __float2bfloat16(x[i]); }
    else if (i < NX + NBTH){
      long j = i - NX; int n = (int)(j >> 9), k = (int)(j & 511);
      int g = n >> 9, hid = n & 511;
      bth[j] = __float2bfloat16(WG[g][(size_t)(256 + k)*512 + hid]);
    } else if (i < NX + NBTH + NBTQ){
      long j = i - NX - NBTH; int n = (int)(j >> 9), k = (int)(j & 511);
      int w = n >> 9, c = n & 511;
      btqkv[j] = __float2bfloat16(WQ[w][(size_t)k*512 + c]);
    } else if (i < NX + NBTH + NBTQ + NBTX){
      long j = i - NX - NBTH - NBTQ; int n = (int)(j >> 8), k = (int)(j & 255);
      int g = n >> 9, hid = n & 511;
      btx[j] = __float2bfloat16(WG[g][(size_t)k*512 + hid]);
    } else if (i < NX + NBTH + NBTQ + NBTX + NF){
      flags[i - NX - NBTH - NBTQ - NBTX] = 0;
    } else if (i < NX + NBTH + NBTQ + NBTX + NF + 2048){
      long j = i - NX - NBTH - NBTQ - NBTX - NF; int g = (int)(j >> 9), hid = (int)(j & 511);
      bias4[j] = BG[g][hid];
    } else if (i < NX + NBTH + NBTQ + NBTX + NF + 2048 + 1536){
      long j = i - NX - NBTH - NBTQ - NBTX - NF - 2048; int w = (int)(j >> 9), c = (int)(j & 511);
      biasq[j] = BQ[w][c];
    } else {
      claim[0] = 0;
    }
  }
}

// ================= K1: persistent LSTM recurrence, XCD0-pinned ===========
// 512 blocks launched; first 32 blocks landing on XCD 0 claim worker slots.
// All cross-block traffic stays inside XCD0's 4MiB L2.
// Round-4 handshake = round-2's PROVEN ordering skeleton (__syncthreads
// everywhere = real compiler+HW barriers; per-block volatile flag stores;
// plain cached h loads — every lout/flag address is fresh per step) with
// only the contention reduced:
//   - ONLY WAVE 0 of each block polls the 32-flag line (32 pollers instead
//     of 256 waves), tight spin, no s_sleep; result broadcast by the
//     following __syncthreads (memory barrier -> no load-hoisting hazard,
//     unlike round-3's raw s_barrier which broke correctness).
//   - x fragments for t+1 prefetched inside the gates section (bounded by
//     barrier1/barrier2, both __syncthreads) — in flight under ~400cy of
//     transcendental VALU, zero extra VGPRs, no sched-barrier tricks.
__global__ __launch_bounds__(512) void k1_lstm(const bf16* xbf, const bf16* btx, const bf16* bth,
                                               const float* bias4, bf16* lout, int* flags,
                                               int* claim, float* out_tail)
{
  __shared__ int s_ns;
  int xcc = (int)(__builtin_amdgcn_s_getreg(GETREG_XCC_ID) & 15);
  if (threadIdx.x == 0){
    int nsl = -1;
    if (xcc == 0){
      nsl = __hip_atomic_fetch_add(claim, 1, __ATOMIC_RELAXED, __HIP_MEMORY_SCOPE_AGENT);
      if (nsl >= 32) nsl = -1;
    }
    s_ns = nsl;
  }
  __syncthreads();
  int ns = s_ns;
  if (ns < 0) return;

  int tid = threadIdx.x, w = tid >> 6, lane = tid & 63;
  int mt = w >> 1, nh = w & 1, lm = lane & 15, q = lane >> 4;
  __shared__ float pre[64][68];

  // resident B-fragments: 2 gates (2*nh, 2*nh+1)
  s8 Bh[2][16], Bx[2][8];
  #pragma unroll
  for (int i = 0; i < 2; ++i){
    const bf16* bph = bth + ((size_t)((2*nh+i)*512 + ns*16 + lm)) * 512;
    #pragma unroll
    for (int kk = 0; kk < 16; ++kk) Bh[i][kk] = ldg8(bph + kk*32 + q*8);
    const bf16* bpx = btx + ((size_t)((2*nh+i)*512 + ns*16 + lm)) * 256;
    #pragma unroll
    for (int kk = 0; kk < 8; ++kk) Bx[i][kk] = ldg8(bpx + kk*32 + q*8);
  }
  // elementwise cells: thread owns (b0, j0) and (b0, j0+1)
  int c0 = 2*tid, b0 = c0 >> 4, j0 = c0 & 15;
  float bs[8];
  #pragma unroll
  for (int g = 0; g < 4; ++g){
    bs[g]   = bias4[g*512 + ns*16 + j0];
    bs[4+g] = bias4[g*512 + ns*16 + j0 + 1];
  }
  float cs0 = 0.f, cs1 = 0.f;
  int budget = 1 << 25;   // tight-spin bailout (loud failure, no hang)

  // x fragments, single buffer, reloaded in gates section for t+1
  s8 Ax[8];
  {
    const bf16* xr = xbf + ((size_t)(0*64 + mt*16 + lm)) * 256;
    #pragma unroll
    for (int kk = 0; kk < 8; ++kk) Ax[kk] = ldg8(xr + kk*32 + q*8);
  }

  for (int t = 0; t < 512; ++t){
    // x-part GEMM (fragments prefetched last iteration)
    f4 acc0 = {0,0,0,0}, acc1 = {0,0,0,0};
    #pragma unroll
    for (int kk = 0; kk < 8; ++kk){
      acc0 = MFMA16(Ax[kk], Bx[0][kk], acc0);
      acc1 = MFMA16(Ax[kk], Bx[1][kk], acc1);
    }
    if (t > 0){
      if (w == 0){
        const int* fp = flags + (size_t)(t-1)*32 + (lane & 31);
        while (budget > 0){
          int v;
          asm volatile("global_load_dword %0, %1, off sc0\n\ts_waitcnt vmcnt(0)"
                       : "=v"(v) : "v"(fp) : "memory");
          if (__ballot(v != 0) == ~0ull) break;
          budget--;
        }
      }
      __syncthreads();   // real barrier: broadcasts poll result, orders h loads
      const bf16* hr = lout + ((size_t)((t-1)*64 + mt*16 + lm)) * 512;
      #pragma unroll
      for (int kk = 0; kk < 16; ++kk){
        s8 Ah = ldg8(hr + kk*32 + q*8);
        acc0 = MFMA16(Ah, Bh[0][kk], acc0);
        acc1 = MFMA16(Ah, Bh[1][kk], acc1);
      }
    }
    // pre-activations -> LDS
    #pragma unroll
    for (int i = 0; i < 2; ++i){
      int col = (2*nh+i)*16 + lm;
      f4 av = (i == 0) ? acc0 : acc1;
      #pragma unroll
      for (int r = 0; r < 4; ++r) pre[mt*16 + q*4 + r][col] = av[r];
    }
    __syncthreads();   // barrier1
    // x prefetch for t+1 — in flight during the gates' transcendental VALU,
    // drained by barrier2's vmcnt(0). Bounded by real barriers on both sides.
    if (t < 511){
      const bf16* xr = xbf + ((size_t)((t+1)*64 + mt*16 + lm)) * 256;
      #pragma unroll
      for (int kk = 0; kk < 8; ++kk) Ax[kk] = ldg8(xr + kk*32 + q*8);
    }
    // elementwise gates for 2 cells
    {
      float fh0 = pre[b0][ 0+j0] + bs[0], fh1 = pre[b0][ 0+j0+1] + bs[4];
      float ih0 = pre[b0][16+j0] + bs[1], ih1 = pre[b0][16+j0+1] + bs[5];
      float gh0 = pre[b0][32+j0] + bs[2], gh1 = pre[b0][32+j0+1] + bs[6];
      float oh0 = pre[b0][48+j0] + bs[3], oh1 = pre[b0][48+j0+1] + bs[7];
      cs0 = sigf(fh0)*cs0 + sigf(ih0)*tanhf_(gh0);
      cs1 = sigf(fh1)*cs1 + sigf(ih1)*tanhf_(gh1);
      float h0v = sigf(oh0)*tanhf_(cs0);
      float h1v = sigf(oh1)*tanhf_(cs1);
      unsigned hv = (unsigned)(unsigned short)f2bs(h0v) | ((unsigned)(unsigned short)f2bs(h1v) << 16);
      // plain store: write-through L1 -> lands in XCD0 L2 (the sync domain)
      *(unsigned*)(lout + ((size_t)(t*64 + b0))*512 + ns*16 + j0) = hv;
      if (t == 511){
        float* hx = out_tail + (size_t)b0*512 + ns*16 + j0;
        hx[0] = h0v; hx[1] = h1v;
        float* cx = out_tail + 32768 + (size_t)b0*512 + ns*16 + j0;
        cx[0] = cs0; cx[1] = cs1;
      }
    }
    __syncthreads();   // barrier2: implies vmcnt(0) -> h stores drained to L2
    if (tid == 0)
      *(volatile int*)(flags + (size_t)t*32 + ns) = 1;
  }
}

// ================= K2: fused QKV GEMM (N=1536), V written transposed =====
// grid (24, 512), 512 thr. Tile 64x64, K=512.
__global__ __launch_bounds__(512) void k2_qkv(const bf16* lout, const bf16* btqkv, const float* biasq,
                                              bf16* yq, bf16* yk, bf16* vt)
{
  int nb = blockIdx.x, rb = blockIdx.y;
  int tid = threadIdx.x, w = tid >> 6, lane = tid & 63;
  int mt = w >> 1, nh = w & 1, lm = lane & 15, q = lane >> 4;
  int row = rb*64 + mt*16 + lm;
  f4 acc[2] = {{0,0,0,0},{0,0,0,0}};
  const bf16* ap  = lout + (size_t)row * 512;
  const bf16* bp0 = btqkv + ((size_t)(nb*64 + (2*nh+0)*16 + lm)) * 512;
  const bf16* bp1 = btqkv + ((size_t)(nb*64 + (2*nh+1)*16 + lm)) * 512;
  #pragma unroll
  for (int kk = 0; kk < 16; ++kk){
    int kb = kk*32 + q*8;
    s8 A = ldg8(ap + kb);
    acc[0] = MFMA16(A, ldg8(bp0 + kb), acc[0]);
    acc[1] = MFMA16(A, ldg8(bp1 + kb), acc[1]);
  }
  #pragma unroll
  for (int i = 0; i < 2; ++i){
    int e = nb*64 + (2*nh+i)*16 + lm;
    float bias = biasq[e];
    #pragma unroll
    for (int r = 0; r < 4; ++r){
      int rr = rb*64 + mt*16 + q*4 + r;
      bf16 v = __float2bfloat16(acc[i][r] + bias);
      if (e < 512)        yq[(size_t)rr*512 + e] = v;
      else if (e < 1024)  yk[(size_t)rr*512 + (e-512)] = v;
      else {
        int d = e - 1024, hh = d >> 7, dh = d & 127;
        vt[((size_t)((rr >> 9)*4 + hh)*128 + dh)*512 + (rr & 511)] = v;
      }
    }
  }
}

// ================= K3: fused scores + softmax + PV -> decoded ============
// grid (8 rowblocks, 256 bh), 256 thr (4 waves, wave = 16-row Q tile).
// LDS: 64KiB union — sK[128][128] during scores, sP[64][512] (XOR-swizzled)
// for the P layout round-trip into the PV MFMA A-operand.
__global__ __launch_bounds__(256) void k3_attn(const bf16* yq, const bf16* yk, const bf16* vt,
                                               float* dec)
{
  int rb = blockIdx.x, bh = blockIdx.y;
  int b1 = bh >> 2, hh = bh & 3;
  int tid = threadIdx.x, w = tid >> 6, lane = tid & 63, lm = lane & 15, q = lane >> 4;
  __shared__ short sbuf[32768];             // 64KiB
  short (*sK)[128] = (short(*)[128])sbuf;   // 16384 shorts = 32KiB
  // A fragments (Q rows), K=128 -> 4 k-steps
  s8 Af[4];
  const bf16* apr = yq + ((size_t)(b1*512 + rb*64 + w*16 + lm))*512 + hh*128;
  #pragma unroll
  for (int kk = 0; kk < 4; ++kk) Af[kk] = ldg8(apr + kk*32 + q*8);
  f4 acc[32];
  #pragma unroll
  for (int nt = 0; nt < 32; ++nt) acc[nt] = (f4){0,0,0,0};

  for (int ch = 0; ch < 4; ++ch){
    __syncthreads();
    #pragma unroll
    for (int it = 0; it < 8; ++it){
      int lin = tid + it*256;              // 0..2047
      int srow = lin >> 4, seg = lin & 15; // 16 segs of 8 bf16
      int pseg = seg ^ (srow & 15);        // swizzle
      *(s8*)&sK[srow][pseg*8] =
        ldg8(yk + ((size_t)(b1*512 + ch*128 + srow))*512 + hh*128 + seg*8);
    }
    __syncthreads();
    #pragma unroll
    for (int ntl = 0; ntl < 8; ++ntl){
      int nt = ch*8 + ntl;
      int brow = ntl*16 + lm;
      #pragma unroll
      for (int kk = 0; kk < 4; ++kk){
        int c = (kk*4 + q) ^ lm;           // de-swizzle
        s8 Bfr = *(const s8*)&sK[brow][c*8];
        acc[nt] = MFMA16(Af[kk], Bfr, acc[nt]);
      }
    }
  }
  // softmax over the full 512-col row (16 lanes x 32 n-tiles)
  const float scale = 0.08838834764831845f;  // 1/sqrt(128)
  float mx[4], sm[4];
  #pragma unroll
  for (int r = 0; r < 4; ++r){
    float m = -1e30f;
    #pragma unroll
    for (int nt = 0; nt < 32; ++nt) m = fmaxf(m, acc[nt][r]);
    mx[r] = m;
  }
  #pragma unroll
  for (int d = 1; d < 16; d <<= 1){
    #pragma unroll
    for (int r = 0; r < 4; ++r) mx[r] = fmaxf(mx[r], __shfl_xor(mx[r], d, 64));
  }
  #pragma unroll
  for (int r = 0; r < 4; ++r){
    float s = 0.f;
    #pragma unroll
    for (int nt = 0; nt < 32; ++nt){
      float e = __expf(scale * (acc[nt][r] - mx[r]));
      acc[nt][r] = e; s += e;
    }
    sm[r] = s;
  }
  #pragma unroll
  for (int d = 1; d < 16; d <<= 1){
    #pragma unroll
    for (int r = 0; r < 4; ++r) sm[r] += __shfl_xor(sm[r], d, 64);
  }
  float inv[4];
  #pragma unroll
  for (int r = 0; r < 4; ++r) inv[r] = 1.f / sm[r];

  __syncthreads();   // all sK reads done before sP overwrites the buffer
  // P tile -> LDS, XOR-swizzled 16B chunks: phys = row*512 + ((col>>3)^(row&15))*8 + (col&7)
  #pragma unroll
  for (int nt = 0; nt < 32; ++nt){
    #pragma unroll
    for (int r = 0; r < 4; ++r){
      int rowp = w*16 + q*4 + r, col = nt*16 + lm;
      sbuf[rowp*512 + (((col >> 3) ^ (rowp & 15))*8) + (col & 7)] =
        f2bs(acc[nt][r] * inv[r]);
    }
  }
  // PV: wave-local (each wave reads only rows it wrote) — no barrier needed
  f4 o[8];
  #pragma unroll
  for (int n2 = 0; n2 < 8; ++n2) o[n2] = (f4){0,0,0,0};
  int rowa = w*16 + lm;
  #pragma unroll
  for (int kk = 0; kk < 16; ++kk){
    s8 A = *(const s8*)&sbuf[rowa*512 + (((kk*4 + q) ^ (rowa & 15))*8)];
    #pragma unroll
    for (int n2 = 0; n2 < 8; ++n2){
      s8 Bfr = ldg8(vt + ((size_t)(bh*128 + n2*16 + lm))*512 + kk*32 + q*8);
      o[n2] = MFMA16(A, Bfr, o[n2]);
    }
  }
  #pragma unroll
  for (int n2 = 0; n2 < 8; ++n2){
    int d = n2*16 + lm;
    #pragma unroll
    for (int r = 0; r < 4; ++r){
      int s1 = rb*64 + w*16 + q*4 + r;
      dec[((size_t)s1*64 + b1)*512 + hh*128 + d] = o[n2][r];
    }
  }
}

// ================= launcher =================
extern "C" void kernel_launch(void* const* d_in, const int* in_sizes, int n_in,
                              void* d_out, int out_size, void* d_ws, size_t ws_size,
                              hipStream_t stream)
{
  const float* x   = (const float*)d_in[0];
  const float* Wf  = (const float*)d_in[1];  const float* bfv = (const float*)d_in[2];
  const float* Wi  = (const float*)d_in[3];  const float* biv = (const float*)d_in[4];
  const float* Wg  = (const float*)d_in[5];  const float* bgv = (const float*)d_in[6];
  const float* Wo  = (const float*)d_in[7];  const float* bov = (const float*)d_in[8];
  const float* Wq  = (const float*)d_in[9];  const float* bqv = (const float*)d_in[10];
  const float* Wk  = (const float*)d_in[11]; const float* bkv = (const float*)d_in[12];
  const float* Wv  = (const float*)d_in[13]; const float* bvv = (const float*)d_in[14];

  char* ws = (char*)d_ws;
  int*   flags = (int*)  (ws + OF_FLAGS);
  float* bias4 = (float*)(ws + OF_BIAS4);
  float* biasq = (float*)(ws + OF_BIASQ);
  int*   claim = (int*)  (ws + OF_CLAIM);
  bf16*  btx   = (bf16*) (ws + OF_BTX);
  bf16*  bth   = (bf16*) (ws + OF_BTH);
  bf16*  btqkv = (bf16*) (ws + OF_BTQKV);
  bf16*  yq    = (bf16*) (ws + OF_YQ);
  bf16*  yk    = (bf16*) (ws + OF_YK);
  bf16*  vt    = (bf16*) (ws + OF_VT);

  char* outc = (char*)d_out;
  bf16*  lout = (bf16*)(outc + DOUT_LOUT);   // dead before decode writes
  bf16*  xbf  = (bf16*)(outc + DOUT_XBF);    // dead before decode writes
  float* out  = (float*)d_out;

  hipLaunchKernelGGL(k0_pack, dim3(2048), dim3(256), 0, stream,
                     x, Wf, Wi, Wg, Wo, bfv, biv, bgv, bov, Wq, Wk, Wv, bqv, bkv, bvv,
                     xbf, btx, bth, btqkv, bias4, biasq, flags, claim);
  hipLaunchKernelGGL(k1_lstm, dim3(512), dim3(512), 0, stream,
                     xbf, btx, bth, bias4, lout, flags, claim, out + DEC_SZ);
  hipLaunchKernelGGL(k2_qkv, dim3(24, 512), dim3(512), 0, stream, lout, btqkv, biasq, yq, yk, vt);
  hipLaunchKernelGGL(k3_attn, dim3(8, 256), dim3(256), 0, stream, yq, yk, vt, out);
}

// Round 5
// 5046.038 us; speedup vs baseline: 1.0121x; 1.0121x over previous
//
#include <hip/hip_runtime.h>
#include <hip/hip_bf16.h>

typedef __attribute__((ext_vector_type(8))) short s8;
typedef __attribute__((ext_vector_type(4))) float f4;

using bf16 = __hip_bfloat16;

#define MFMA16(a,b,c) __builtin_amdgcn_mfma_f32_16x16x32_bf16((a),(b),(c),0,0,0)

// HW_REG_XCC_ID (id=20), offset 0, width 4  ->  simm16 = id | (off<<6) | ((w-1)<<11)
#define GETREG_XCC_ID (20 | (0 << 6) | (3 << 11))

// ---------------- sizes ----------------
constexpr int SS = 512, BBATCH = 64, HIDN = 512;
constexpr size_t DEC_SZ = (size_t)SS * BBATCH * HIDN;  // 16777216 f32 = 64MiB

// ---------------- ws layout (bytes), total 101 MiB ----------------
// flags: SCATTERED layout flag[ns][t] = flags[ns*512 + t] — each producer
// signals on its OWN cache line (per-step line per producer = line
// (ns*512+t)>>5). The 32-flag gather hits 32 DISTINCT L2 banks in parallel,
// eliminating the single hot bank that round-0/2/4 polling saturated.
constexpr size_t OF_FLAGS = 0;                  // 32*512*4 = 64KiB
constexpr size_t OF_BIAS4 = 65536;              // 2048 f32
constexpr size_t OF_BIASQ = 73728;              // 1536 f32  (ends 79872)
constexpr size_t OF_CLAIM = 81920;              // 1 int (worker-slot counter)
constexpr size_t OF_BTX   = 131072;             // Bt_x [2048][256] bf16 = 1MiB
constexpr size_t OF_BTH   = 1179648;            // Bt_h [2048][512] bf16 = 2MiB
constexpr size_t OF_BTQKV = 3276800;            // Bt_qkv [1536][512] bf16 = 1.5MiB
constexpr size_t OF_YQ    = (size_t)5  << 20;   // 32MiB
constexpr size_t OF_YK    = OF_YQ + ((size_t)32 << 20);
constexpr size_t OF_VT    = OF_YK + ((size_t)32 << 20);   // ends at 101MiB

// d_out scratch offsets (inside 64MiB decoded region; dead before decode writes)
constexpr size_t DOUT_LOUT = 0;                 // lout bf16 [32768][512] = 32MiB
constexpr size_t DOUT_XBF  = (size_t)32 << 20;  // xbf bf16 [32768][256] = 16MiB

// ---------------- helpers ----------------
__device__ inline s8 ldg8(const bf16* p){ return *(const s8*)p; }
__device__ inline short f2bs(float f){ return __builtin_bit_cast(short, __float2bfloat16(f)); }
__device__ inline float sigf(float x){ return 1.f/(1.f + __expf(-x)); }
__device__ inline float tanhf_(float x){ x = fminf(fmaxf(x, -15.f), 15.f); float e = __expf(2.f*x); return (e-1.f)/(e+1.f); }

// ================= K0: pack weights/biases/x, zero flags =================
__global__ void k0_pack(const float* x,
                        const float* Wf,const float* Wi,const float* Wg,const float* Wo,
                        const float* bfv,const float* biv,const float* bgv,const float* bov,
                        const float* Wq,const float* Wk,const float* Wv,
                        const float* bqv,const float* bkv,const float* bvv,
                        bf16* xbf, bf16* btx, bf16* bth, bf16* btqkv,
                        float* bias4, float* biasq, int* flags, int* claim)
{
  const float* WG[4] = {Wf, Wi, Wg, Wo};
  const float* BG[4] = {bfv, biv, bgv, bov};
  const float* WQ[3] = {Wq, Wk, Wv};
  const float* BQ[3] = {bqv, bkv, bvv};
  const long NX   = 8388608;   // 32768*256
  const long NBTH = 1048576;   // 2048*512
  const long NBTQ = 786432;    // 1536*512
  const long NBTX = 524288;    // 2048*256
  const long NF   = 16384;     // 32*512
  const long TOT  = NX + NBTH + NBTQ + NBTX + NF + 2048 + 1536 + 1;
  long stride = (long)gridDim.x * blockDim.x;
  for (long i = (long)blockIdx.x*blockDim.x + threadIdx.x; i < TOT; i += stride){
    if (i < NX){ xbf[i] = __float2bfloat16(x[i]); }
    else if (i < NX + NBTH){
      long j = i - NX; int n = (int)(j >> 9), k = (int)(j & 511);
      int g = n >> 9, hid = n & 511;
      bth[j] = __float2bfloat16(WG[g][(size_t)(256 + k)*512 + hid]);
    } else if (i < NX + NBTH + NBTQ){
      long j = i - NX - NBTH; int n = (int)(j >> 9), k = (int)(j & 511);
      int w = n >> 9, c = n & 511;
      btqkv[j] = __float2bfloat16(WQ[w][(size_t)k*512 + c]);
    } else if (i < NX + NBTH + NBTQ + NBTX){
      long j = i - NX - NBTH - NBTQ; int n = (int)(j >> 8), k = (int)(j & 255);
      int g = n >> 9, hid = n & 511;
      btx[j] = __float2bfloat16(WG[g][(size_t)k*512 + hid]);
    } else if (i < NX + NBTH + NBTQ + NBTX + NF){
      flags[i - NX - NBTH - NBTQ - NBTX] = 0;
    } else if (i < NX + NBTH + NBTQ + NBTX + NF + 2048){
      long j = i - NX - NBTH - NBTQ - NBTX - NF; int g = (int)(j >> 9), hid = (int)(j & 511);
      bias4[j] = BG[g][hid];
    } else if (i < NX + NBTH + NBTQ + NBTX + NF + 2048 + 1536){
      long j = i - NX - NBTH - NBTQ - NBTX - NF - 2048; int w = (int)(j >> 9), c = (int)(j & 511);
      biasq[j] = BQ[w][c];
    } else {
      claim[0] = 0;
    }
  }
}

// ================= K1: persistent LSTM recurrence, XCD0-pinned ===========
// 512 blocks launched; first 32 blocks landing on XCD 0 claim worker slots.
// All cross-block traffic stays inside XCD0's 4MiB L2.
// Round-5 handshake: round-4's PROVEN-correct ordering skeleton
// (__syncthreads everywhere; per-block volatile flag stores; plain cached
// h loads — every lout/flag address is fresh per step), with the L2
// contention removed:
//   - flags SCATTERED one line per producer (flag[ns][t]); the single
//     polling wave gathers 32 distinct lines -> 32 different L2 banks in
//     parallel. No hot bank between poll loads and producer flag stores.
//   - s_sleep(1) backoff restored (round-4's tight spin starved the
//     producers' stores -> 3.7s replay outliers).
__global__ __launch_bounds__(512) void k1_lstm(const bf16* xbf, const bf16* btx, const bf16* bth,
                                               const float* bias4, bf16* lout, int* flags,
                                               int* claim, float* out_tail)
{
  __shared__ int s_ns;
  int xcc = (int)(__builtin_amdgcn_s_getreg(GETREG_XCC_ID) & 15);
  if (threadIdx.x == 0){
    int nsl = -1;
    if (xcc == 0){
      nsl = __hip_atomic_fetch_add(claim, 1, __ATOMIC_RELAXED, __HIP_MEMORY_SCOPE_AGENT);
      if (nsl >= 32) nsl = -1;
    }
    s_ns = nsl;
  }
  __syncthreads();
  int ns = s_ns;
  if (ns < 0) return;

  int tid = threadIdx.x, w = tid >> 6, lane = tid & 63;
  int mt = w >> 1, nh = w & 1, lm = lane & 15, q = lane >> 4;
  __shared__ float pre[64][68];

  // resident B-fragments: 2 gates (2*nh, 2*nh+1)
  s8 Bh[2][16], Bx[2][8];
  #pragma unroll
  for (int i = 0; i < 2; ++i){
    const bf16* bph = bth + ((size_t)((2*nh+i)*512 + ns*16 + lm)) * 512;
    #pragma unroll
    for (int kk = 0; kk < 16; ++kk) Bh[i][kk] = ldg8(bph + kk*32 + q*8);
    const bf16* bpx = btx + ((size_t)((2*nh+i)*512 + ns*16 + lm)) * 256;
    #pragma unroll
    for (int kk = 0; kk < 8; ++kk) Bx[i][kk] = ldg8(bpx + kk*32 + q*8);
  }
  // elementwise cells: thread owns (b0, j0) and (b0, j0+1)
  int c0 = 2*tid, b0 = c0 >> 4, j0 = c0 & 15;
  float bs[8];
  #pragma unroll
  for (int g = 0; g < 4; ++g){
    bs[g]   = bias4[g*512 + ns*16 + j0];
    bs[4+g] = bias4[g*512 + ns*16 + j0 + 1];
  }
  float cs0 = 0.f, cs1 = 0.f;
  int budget = 1 << 22;   // spin bailout (loud failure, bounded; ~0.8s max)

  // x fragments, single buffer, reloaded in gates section for t+1
  s8 Ax[8];
  {
    const bf16* xr = xbf + ((size_t)(0*64 + mt*16 + lm)) * 256;
    #pragma unroll
    for (int kk = 0; kk < 8; ++kk) Ax[kk] = ldg8(xr + kk*32 + q*8);
  }

  for (int t = 0; t < 512; ++t){
    // x-part GEMM (fragments prefetched last iteration)
    f4 acc0 = {0,0,0,0}, acc1 = {0,0,0,0};
    #pragma unroll
    for (int kk = 0; kk < 8; ++kk){
      acc0 = MFMA16(Ax[kk], Bx[0][kk], acc0);
      acc1 = MFMA16(Ax[kk], Bx[1][kk], acc1);
    }
    if (t > 0){
      if (w == 0){
        // lane i (i<32) polls producer i's private line: flags[i*512 + t-1]
        const int* fp = flags + ((size_t)(lane & 31) * 512) + (t-1);
        while (budget > 0){
          int v = 1;
          if (lane < 32){
            asm volatile("global_load_dword %0, %1, off sc0\n\ts_waitcnt vmcnt(0)"
                         : "=v"(v) : "v"(fp) : "memory");
          }
          if (__ballot(v != 0) == ~0ull) break;
          budget--;
          __builtin_amdgcn_s_sleep(1);
        }
      }
      __syncthreads();   // real barrier: broadcasts poll result, orders h loads
      const bf16* hr = lout + ((size_t)((t-1)*64 + mt*16 + lm)) * 512;
      #pragma unroll
      for (int kk = 0; kk < 16; ++kk){
        s8 Ah = ldg8(hr + kk*32 + q*8);
        acc0 = MFMA16(Ah, Bh[0][kk], acc0);
        acc1 = MFMA16(Ah, Bh[1][kk], acc1);
      }
    }
    // pre-activations -> LDS
    #pragma unroll
    for (int i = 0; i < 2; ++i){
      int col = (2*nh+i)*16 + lm;
      f4 av = (i == 0) ? acc0 : acc1;
      #pragma unroll
      for (int r = 0; r < 4; ++r) pre[mt*16 + q*4 + r][col] = av[r];
    }
    __syncthreads();   // barrier1
    // x prefetch for t+1 — in flight during the gates' transcendental VALU,
    // drained by barrier2's vmcnt(0). Bounded by real barriers on both sides.
    if (t < 511){
      const bf16* xr = xbf + ((size_t)((t+1)*64 + mt*16 + lm)) * 256;
      #pragma unroll
      for (int kk = 0; kk < 8; ++kk) Ax[kk] = ldg8(xr + kk*32 + q*8);
    }
    // elementwise gates for 2 cells
    {
      float fh0 = pre[b0][ 0+j0] + bs[0], fh1 = pre[b0][ 0+j0+1] + bs[4];
      float ih0 = pre[b0][16+j0] + bs[1], ih1 = pre[b0][16+j0+1] + bs[5];
      float gh0 = pre[b0][32+j0] + bs[2], gh1 = pre[b0][32+j0+1] + bs[6];
      float oh0 = pre[b0][48+j0] + bs[3], oh1 = pre[b0][48+j0+1] + bs[7];
      cs0 = sigf(fh0)*cs0 + sigf(ih0)*tanhf_(gh0);
      cs1 = sigf(fh1)*cs1 + sigf(ih1)*tanhf_(gh1);
      float h0v = sigf(oh0)*tanhf_(cs0);
      float h1v = sigf(oh1)*tanhf_(cs1);
      unsigned hv = (unsigned)(unsigned short)f2bs(h0v) | ((unsigned)(unsigned short)f2bs(h1v) << 16);
      // plain store: write-through L1 -> lands in XCD0 L2 (the sync domain)
      *(unsigned*)(lout + ((size_t)(t*64 + b0))*512 + ns*16 + j0) = hv;
      if (t == 511){
        float* hx = out_tail + (size_t)b0*512 + ns*16 + j0;
        hx[0] = h0v; hx[1] = h1v;
        float* cx = out_tail + 32768 + (size_t)b0*512 + ns*16 + j0;
        cx[0] = cs0; cx[1] = cs1;
      }
    }
    __syncthreads();   // barrier2: implies vmcnt(0) -> h stores drained to L2
    if (tid == 0)
      *(volatile int*)(flags + (size_t)ns*512 + t) = 1;
  }
}

// ================= K2: fused QKV GEMM (N=1536), V written transposed =====
// grid (24, 512), 512 thr. Tile 64x64, K=512.
__global__ __launch_bounds__(512) void k2_qkv(const bf16* lout, const bf16* btqkv, const float* biasq,
                                              bf16* yq, bf16* yk, bf16* vt)
{
  int nb = blockIdx.x, rb = blockIdx.y;
  int tid = threadIdx.x, w = tid >> 6, lane = tid & 63;
  int mt = w >> 1, nh = w & 1, lm = lane & 15, q = lane >> 4;
  int row = rb*64 + mt*16 + lm;
  f4 acc[2] = {{0,0,0,0},{0,0,0,0}};
  const bf16* ap  = lout + (size_t)row * 512;
  const bf16* bp0 = btqkv + ((size_t)(nb*64 + (2*nh+0)*16 + lm)) * 512;
  const bf16* bp1 = btqkv + ((size_t)(nb*64 + (2*nh+1)*16 + lm)) * 512;
  #pragma unroll
  for (int kk = 0; kk < 16; ++kk){
    int kb = kk*32 + q*8;
    s8 A = ldg8(ap + kb);
    acc[0] = MFMA16(A, ldg8(bp0 + kb), acc[0]);
    acc[1] = MFMA16(A, ldg8(bp1 + kb), acc[1]);
  }
  #pragma unroll
  for (int i = 0; i < 2; ++i){
    int e = nb*64 + (2*nh+i)*16 + lm;
    float bias = biasq[e];
    #pragma unroll
    for (int r = 0; r < 4; ++r){
      int rr = rb*64 + mt*16 + q*4 + r;
      bf16 v = __float2bfloat16(acc[i][r] + bias);
      if (e < 512)        yq[(size_t)rr*512 + e] = v;
      else if (e < 1024)  yk[(size_t)rr*512 + (e-512)] = v;
      else {
        int d = e - 1024, hh = d >> 7, dh = d & 127;
        vt[((size_t)((rr >> 9)*4 + hh)*128 + dh)*512 + (rr & 511)] = v;
      }
    }
  }
}

// ================= K3: fused scores + softmax + PV -> decoded ============
// grid (8 rowblocks, 256 bh), 256 thr (4 waves, wave = 16-row Q tile).
// LDS: 64KiB union — sK[128][128] during scores, sP[64][512] (XOR-swizzled)
// for the P layout round-trip into the PV MFMA A-operand.
__global__ __launch_bounds__(256) void k3_attn(const bf16* yq, const bf16* yk, const bf16* vt,
                                               float* dec)
{
  int rb = blockIdx.x, bh = blockIdx.y;
  int b1 = bh >> 2, hh = bh & 3;
  int tid = threadIdx.x, w = tid >> 6, lane = tid & 63, lm = lane & 15, q = lane >> 4;
  __shared__ short sbuf[32768];             // 64KiB
  short (*sK)[128] = (short(*)[128])sbuf;   // 16384 shorts = 32KiB
  // A fragments (Q rows), K=128 -> 4 k-steps
  s8 Af[4];
  const bf16* apr = yq + ((size_t)(b1*512 + rb*64 + w*16 + lm))*512 + hh*128;
  #pragma unroll
  for (int kk = 0; kk < 4; ++kk) Af[kk] = ldg8(apr + kk*32 + q*8);
  f4 acc[32];
  #pragma unroll
  for (int nt = 0; nt < 32; ++nt) acc[nt] = (f4){0,0,0,0};

  for (int ch = 0; ch < 4; ++ch){
    __syncthreads();
    #pragma unroll
    for (int it = 0; it < 8; ++it){
      int lin = tid + it*256;              // 0..2047
      int srow = lin >> 4, seg = lin & 15; // 16 segs of 8 bf16
      int pseg = seg ^ (srow & 15);        // swizzle
      *(s8*)&sK[srow][pseg*8] =
        ldg8(yk + ((size_t)(b1*512 + ch*128 + srow))*512 + hh*128 + seg*8);
    }
    __syncthreads();
    #pragma unroll
    for (int ntl = 0; ntl < 8; ++ntl){
      int nt = ch*8 + ntl;
      int brow = ntl*16 + lm;
      #pragma unroll
      for (int kk = 0; kk < 4; ++kk){
        int c = (kk*4 + q) ^ lm;           // de-swizzle
        s8 Bfr = *(const s8*)&sK[brow][c*8];
        acc[nt] = MFMA16(Af[kk], Bfr, acc[nt]);
      }
    }
  }
  // softmax over the full 512-col row (16 lanes x 32 n-tiles)
  const float scale = 0.08838834764831845f;  // 1/sqrt(128)
  float mx[4], sm[4];
  #pragma unroll
  for (int r = 0; r < 4; ++r){
    float m = -1e30f;
    #pragma unroll
    for (int nt = 0; nt < 32; ++nt) m = fmaxf(m, acc[nt][r]);
    mx[r] = m;
  }
  #pragma unroll
  for (int d = 1; d < 16; d <<= 1){
    #pragma unroll
    for (int r = 0; r < 4; ++r) mx[r] = fmaxf(mx[r], __shfl_xor(mx[r], d, 64));
  }
  #pragma unroll
  for (int r = 0; r < 4; ++r){
    float s = 0.f;
    #pragma unroll
    for (int nt = 0; nt < 32; ++nt){
      float e = __expf(scale * (acc[nt][r] - mx[r]));
      acc[nt][r] = e; s += e;
    }
    sm[r] = s;
  }
  #pragma unroll
  for (int d = 1; d < 16; d <<= 1){
    #pragma unroll
    for (int r = 0; r < 4; ++r) sm[r] += __shfl_xor(sm[r], d, 64);
  }
  float inv[4];
  #pragma unroll
  for (int r = 0; r < 4; ++r) inv[r] = 1.f / sm[r];

  __syncthreads();   // all sK reads done before sP overwrites the buffer
  // P tile -> LDS, XOR-swizzled 16B chunks: phys = row*512 + ((col>>3)^(row&15))*8 + (col&7)
  #pragma unroll
  for (int nt = 0; nt < 32; ++nt){
    #pragma unroll
    for (int r = 0; r < 4; ++r){
      int rowp = w*16 + q*4 + r, col = nt*16 + lm;
      sbuf[rowp*512 + (((col >> 3) ^ (rowp & 15))*8) + (col & 7)] =
        f2bs(acc[nt][r] * inv[r]);
    }
  }
  // PV: wave-local (each wave reads only rows it wrote) — no barrier needed
  f4 o[8];
  #pragma unroll
  for (int n2 = 0; n2 < 8; ++n2) o[n2] = (f4){0,0,0,0};
  int rowa = w*16 + lm;
  #pragma unroll
  for (int kk = 0; kk < 16; ++kk){
    s8 A = *(const s8*)&sbuf[rowa*512 + (((kk*4 + q) ^ (rowa & 15))*8)];
    #pragma unroll
    for (int n2 = 0; n2 < 8; ++n2){
      s8 Bfr = ldg8(vt + ((size_t)(bh*128 + n2*16 + lm))*512 + kk*32 + q*8);
      o[n2] = MFMA16(A, Bfr, o[n2]);
    }
  }
  #pragma unroll
  for (int n2 = 0; n2 < 8; ++n2){
    int d = n2*16 + lm;
    #pragma unroll
    for (int r = 0; r < 4; ++r){
      int s1 = rb*64 + w*16 + q*4 + r;
      dec[((size_t)s1*64 + b1)*512 + hh*128 + d] = o[n2][r];
    }
  }
}

// ================= launcher =================
extern "C" void kernel_launch(void* const* d_in, const int* in_sizes, int n_in,
                              void* d_out, int out_size, void* d_ws, size_t ws_size,
                              hipStream_t stream)
{
  const float* x   = (const float*)d_in[0];
  const float* Wf  = (const float*)d_in[1];  const float* bfv = (const float*)d_in[2];
  const float* Wi  = (const float*)d_in[3];  const float* biv = (const float*)d_in[4];
  const float* Wg  = (const float*)d_in[5];  const float* bgv = (const float*)d_in[6];
  const float* Wo  = (const float*)d_in[7];  const float* bov = (const float*)d_in[8];
  const float* Wq  = (const float*)d_in[9];  const float* bqv = (const float*)d_in[10];
  const float* Wk  = (const float*)d_in[11]; const float* bkv = (const float*)d_in[12];
  const float* Wv  = (const float*)d_in[13]; const float* bvv = (const float*)d_in[14];

  char* ws = (char*)d_ws;
  int*   flags = (int*)  (ws + OF_FLAGS);
  float* bias4 = (float*)(ws + OF_BIAS4);
  float* biasq = (float*)(ws + OF_BIASQ);
  int*   claim = (int*)  (ws + OF_CLAIM);
  bf16*  btx   = (bf16*) (ws + OF_BTX);
  bf16*  bth   = (bf16*) (ws + OF_BTH);
  bf16*  btqkv = (bf16*) (ws + OF_BTQKV);
  bf16*  yq    = (bf16*) (ws + OF_YQ);
  bf16*  yk    = (bf16*) (ws + OF_YK);
  bf16*  vt    = (bf16*) (ws + OF_VT);

  char* outc = (char*)d_out;
  bf16*  lout = (bf16*)(outc + DOUT_LOUT);   // dead before decode writes
  bf16*  xbf  = (bf16*)(outc + DOUT_XBF);    // dead before decode writes
  float* out  = (float*)d_out;

  hipLaunchKernelGGL(k0_pack, dim3(2048), dim3(256), 0, stream,
                     x, Wf, Wi, Wg, Wo, bfv, biv, bgv, bov, Wq, Wk, Wv, bqv, bkv, bvv,
                     xbf, btx, bth, btqkv, bias4, biasq, flags, claim);
  hipLaunchKernelGGL(k1_lstm, dim3(512), dim3(512), 0, stream,
                     xbf, btx, bth, bias4, lout, flags, claim, out + DEC_SZ);
  hipLaunchKernelGGL(k2_qkv, dim3(24, 512), dim3(512), 0, stream, lout, btqkv, biasq, yq, yk, vt);
  hipLaunchKernelGGL(k3_attn, dim3(8, 256), dim3(256), 0, stream, yq, yk, vt, out);
}

// Round 6
// 4368.627 us; speedup vs baseline: 1.1691x; 1.1551x over previous
//
#include <hip/hip_runtime.h>
#include <hip/hip_bf16.h>

typedef __attribute__((ext_vector_type(8))) short s8;
typedef __attribute__((ext_vector_type(4))) float f4;

using bf16 = __hip_bfloat16;

#define MFMA16(a,b,c) __builtin_amdgcn_mfma_f32_16x16x32_bf16((a),(b),(c),0,0,0)

// HW_REG_XCC_ID (id=20), offset 0, width 4  ->  simm16 = id | (off<<6) | ((w-1)<<11)
#define GETREG_XCC_ID (20 | (0 << 6) | (3 << 11))

// ---------------- sizes ----------------
constexpr int SS = 512, BBATCH = 64, HIDN = 512;
constexpr size_t DEC_SZ = (size_t)SS * BBATCH * HIDN;  // 16777216 f32 = 64MiB

// ---------------- ws layout (bytes), total 101 MiB ----------------
constexpr size_t OF_FLAGS = 0;                  // 512*32*4 = 64KiB (one 128B line per step)
constexpr size_t OF_BIAS4 = 65536;              // 2048 f32
constexpr size_t OF_BIASQ = 73728;              // 1536 f32  (ends 79872)
constexpr size_t OF_CLAIM = 81920;              // 1 int (worker-slot counter)
constexpr size_t OF_BTX   = 131072;             // Bt_x [2048][256] bf16 = 1MiB
constexpr size_t OF_BTH   = 1179648;            // Bt_h [2048][512] bf16 = 2MiB
constexpr size_t OF_BTQKV = 3276800;            // Bt_qkv [1536][512] bf16 = 1.5MiB
constexpr size_t OF_YQ    = (size_t)5  << 20;   // 32MiB
constexpr size_t OF_YK    = OF_YQ + ((size_t)32 << 20);
constexpr size_t OF_VT    = OF_YK + ((size_t)32 << 20);   // ends at 101MiB

// d_out scratch offsets (inside 64MiB decoded region; dead before decode writes)
constexpr size_t DOUT_LOUT = 0;                 // lout bf16 [32768][512] = 32MiB
constexpr size_t DOUT_XBF  = (size_t)32 << 20;  // xbf bf16 [32768][256] = 16MiB

// ---------------- helpers ----------------
__device__ inline s8 ldg8(const bf16* p){ return *(const s8*)p; }
__device__ inline short f2bs(float f){ return __builtin_bit_cast(short, __float2bfloat16(f)); }
__device__ inline float sigf(float x){ return 1.f/(1.f + __expf(-x)); }
__device__ inline float tanhf_(float x){ x = fminf(fmaxf(x, -15.f), 15.f); float e = __expf(2.f*x); return (e-1.f)/(e+1.f); }

// ================= K0: pack weights/biases/x, zero flags =================
__global__ void k0_pack(const float* x,
                        const float* Wf,const float* Wi,const float* Wg,const float* Wo,
                        const float* bfv,const float* biv,const float* bgv,const float* bov,
                        const float* Wq,const float* Wk,const float* Wv,
                        const float* bqv,const float* bkv,const float* bvv,
                        bf16* xbf, bf16* btx, bf16* bth, bf16* btqkv,
                        float* bias4, float* biasq, int* flags, int* claim)
{
  const float* WG[4] = {Wf, Wi, Wg, Wo};
  const float* BG[4] = {bfv, biv, bgv, bov};
  const float* WQ[3] = {Wq, Wk, Wv};
  const float* BQ[3] = {bqv, bkv, bvv};
  const long NX   = 8388608;   // 32768*256
  const long NBTH = 1048576;   // 2048*512
  const long NBTQ = 786432;    // 1536*512
  const long NBTX = 524288;    // 2048*256
  const long NF   = 16384;     // 512*32
  const long TOT  = NX + NBTH + NBTQ + NBTX + NF + 2048 + 1536 + 1;
  long stride = (long)gridDim.x * blockDim.x;
  for (long i = (long)blockIdx.x*blockDim.x + threadIdx.x; i < TOT; i += stride){
    if (i < NX){ xbf[i] = __float2bfloat16(x[i]); }
    else if (i < NX + NBTH){
      long j = i - NX; int n = (int)(j >> 9), k = (int)(j & 511);
      int g = n >> 9, hid = n & 511;
      bth[j] = __float2bfloat16(WG[g][(size_t)(256 + k)*512 + hid]);
    } else if (i < NX + NBTH + NBTQ){
      long j = i - NX - NBTH; int n = (int)(j >> 9), k = (int)(j & 511);
      int w = n >> 9, c = n & 511;
      btqkv[j] = __float2bfloat16(WQ[w][(size_t)k*512 + c]);
    } else if (i < NX + NBTH + NBTQ + NBTX){
      long j = i - NX - NBTH - NBTQ; int n = (int)(j >> 8), k = (int)(j & 255);
      int g = n >> 9, hid = n & 511;
      btx[j] = __float2bfloat16(WG[g][(size_t)k*512 + hid]);
    } else if (i < NX + NBTH + NBTQ + NBTX + NF){
      flags[i - NX - NBTH - NBTQ - NBTX] = 0;
    } else if (i < NX + NBTH + NBTQ + NBTX + NF + 2048){
      long j = i - NX - NBTH - NBTQ - NBTX - NF; int g = (int)(j >> 9), hid = (int)(j & 511);
      bias4[j] = BG[g][hid];
    } else if (i < NX + NBTH + NBTQ + NBTX + NF + 2048 + 1536){
      long j = i - NX - NBTH - NBTQ - NBTX - NF - 2048; int w = (int)(j >> 9), c = (int)(j & 511);
      biasq[j] = BQ[w][c];
    } else {
      claim[0] = 0;
    }
  }
}

// ================= K1: persistent LSTM recurrence, XCD0-pinned ===========
// 512 blocks launched; first 32 blocks landing on XCD 0 claim worker slots.
// All cross-block traffic stays inside XCD0's 4MiB L2.
// Round-6 = EXACT round-2 structure (the fastest passing: all-wave poll,
// per-step flag line, volatile flag store, plain cached h loads) with ONE
// change: the s_sleep(1) poll backoff is replaced by a dependent-FMA VALU
// busy chain. Rationale (DVFS theory): k1 is a ~4ms kernel at ~1% VALU/MFMA
// utilization — the SMU's activity-based governor downclocks the GFX domain
// to ~400-500MHz, inflating every latency segment ~5x (explains the 15-18k
// cy/step vs ~3k modeled, and why bandwidth/banking fixes did nothing).
// Busy-waiting presents ~full VALU duty to the activity monitor, holding
// boost clocks while costing nothing on the critical path (same ~128cy
// detection granularity as s_sleep(1)).
__global__ __launch_bounds__(512) void k1_lstm(const bf16* xbf, const bf16* btx, const bf16* bth,
                                               const float* bias4, bf16* lout, int* flags,
                                               int* claim, float* out_tail)
{
  __shared__ int s_ns;
  int xcc = (int)(__builtin_amdgcn_s_getreg(GETREG_XCC_ID) & 15);
  if (threadIdx.x == 0){
    int nsl = -1;
    if (xcc == 0){
      nsl = __hip_atomic_fetch_add(claim, 1, __ATOMIC_RELAXED, __HIP_MEMORY_SCOPE_AGENT);
      if (nsl >= 32) nsl = -1;
    }
    s_ns = nsl;
  }
  __syncthreads();
  int ns = s_ns;
  if (ns < 0) return;

  int tid = threadIdx.x, w = tid >> 6, lane = tid & 63;
  int mt = w >> 1, nh = w & 1, lm = lane & 15, q = lane >> 4;
  __shared__ float pre[64][68];

  // resident B-fragments: 2 gates (2*nh, 2*nh+1)
  s8 Bh[2][16], Bx[2][8];
  #pragma unroll
  for (int i = 0; i < 2; ++i){
    const bf16* bph = bth + ((size_t)((2*nh+i)*512 + ns*16 + lm)) * 512;
    #pragma unroll
    for (int kk = 0; kk < 16; ++kk) Bh[i][kk] = ldg8(bph + kk*32 + q*8);
    const bf16* bpx = btx + ((size_t)((2*nh+i)*512 + ns*16 + lm)) * 256;
    #pragma unroll
    for (int kk = 0; kk < 8; ++kk) Bx[i][kk] = ldg8(bpx + kk*32 + q*8);
  }
  // elementwise cells: thread owns (b0, j0) and (b0, j0+1)
  int c0 = 2*tid, b0 = c0 >> 4, j0 = c0 & 15;
  float bs[8];
  #pragma unroll
  for (int g = 0; g < 4; ++g){
    bs[g]   = bias4[g*512 + ns*16 + j0];
    bs[4+g] = bias4[g*512 + ns*16 + j0 + 1];
  }
  float cs0 = 0.f, cs1 = 0.f;
  float spin = (float)tid;   // busy-wait accumulator (kept live via asm sink)
  int budget = 1 << 22;      // poll bailout (loud failure, bounded)

  for (int t = 0; t < 512; ++t){
    // x-part GEMM (independent of recurrence -> before the poll)
    f4 acc0 = {0,0,0,0}, acc1 = {0,0,0,0};
    const bf16* xr = xbf + ((size_t)(t*64 + mt*16 + lm)) * 256;
    #pragma unroll
    for (int kk = 0; kk < 8; ++kk){
      s8 A = ldg8(xr + kk*32 + q*8);
      acc0 = MFMA16(A, Bx[0][kk], acc0);
      acc1 = MFMA16(A, Bx[1][kk], acc1);
    }
    if (t > 0){
      const int* fp = flags + (size_t)(t-1)*32 + (lane & 31);
      while (budget > 0){
        int v;
        asm volatile("global_load_dword %0, %1, off sc0\n\ts_waitcnt vmcnt(0)"
                     : "=v"(v) : "v"(fp) : "memory");
        if (__ballot(v != 0) == ~0ull) break;
        budget--;
        // busy backoff: ~32 dependent FMAs (~128cy) keep VALU duty high so
        // the activity-based DVFS governor holds boost clocks.
        #pragma unroll
        for (int u = 0; u < 32; ++u) spin = __builtin_fmaf(spin, 1.0000001f, 1e-6f);
        asm volatile("" :: "v"(spin));
      }
      // compiler reorder barrier only; no cache maintenance needed (same-XCD L2)
      __builtin_amdgcn_fence(__ATOMIC_ACQUIRE, "workgroup");
      const bf16* hr = lout + ((size_t)((t-1)*64 + mt*16 + lm)) * 512;
      #pragma unroll
      for (int kk = 0; kk < 16; ++kk){
        s8 Ah = ldg8(hr + kk*32 + q*8);
        acc0 = MFMA16(Ah, Bh[0][kk], acc0);
        acc1 = MFMA16(Ah, Bh[1][kk], acc1);
      }
    }
    // pre-activations -> LDS
    #pragma unroll
    for (int i = 0; i < 2; ++i){
      int col = (2*nh+i)*16 + lm;
      f4 av = (i == 0) ? acc0 : acc1;
      #pragma unroll
      for (int r = 0; r < 4; ++r) pre[mt*16 + q*4 + r][col] = av[r];
    }
    __syncthreads();
    // elementwise gates for 2 cells
    {
      float fh0 = pre[b0][ 0+j0] + bs[0], fh1 = pre[b0][ 0+j0+1] + bs[4];
      float ih0 = pre[b0][16+j0] + bs[1], ih1 = pre[b0][16+j0+1] + bs[5];
      float gh0 = pre[b0][32+j0] + bs[2], gh1 = pre[b0][32+j0+1] + bs[6];
      float oh0 = pre[b0][48+j0] + bs[3], oh1 = pre[b0][48+j0+1] + bs[7];
      cs0 = sigf(fh0)*cs0 + sigf(ih0)*tanhf_(gh0);
      cs1 = sigf(fh1)*cs1 + sigf(ih1)*tanhf_(gh1);
      float h0v = sigf(oh0)*tanhf_(cs0);
      float h1v = sigf(oh1)*tanhf_(cs1);
      unsigned hv = (unsigned)(unsigned short)f2bs(h0v) | ((unsigned)(unsigned short)f2bs(h1v) << 16);
      // plain store: write-through L1 -> lands in XCD0 L2 (the sync domain)
      *(unsigned*)(lout + ((size_t)(t*64 + b0))*512 + ns*16 + j0) = hv;
      if (t == 511){
        float* hx = out_tail + (size_t)b0*512 + ns*16 + j0;
        hx[0] = h0v; hx[1] = h1v;
        float* cx = out_tail + 32768 + (size_t)b0*512 + ns*16 + j0;
        cx[0] = cs0; cx[1] = cs1;
      }
    }
    __syncthreads();   // implies vmcnt(0): all h stores drained to L2
    if (tid == 0)
      *(volatile int*)(flags + (size_t)t*32 + ns) = 1;
  }
}

// ================= K2: fused QKV GEMM (N=1536), V written transposed =====
// grid (24, 512), 512 thr. Tile 64x64, K=512.
__global__ __launch_bounds__(512) void k2_qkv(const bf16* lout, const bf16* btqkv, const float* biasq,
                                              bf16* yq, bf16* yk, bf16* vt)
{
  int nb = blockIdx.x, rb = blockIdx.y;
  int tid = threadIdx.x, w = tid >> 6, lane = tid & 63;
  int mt = w >> 1, nh = w & 1, lm = lane & 15, q = lane >> 4;
  int row = rb*64 + mt*16 + lm;
  f4 acc[2] = {{0,0,0,0},{0,0,0,0}};
  const bf16* ap  = lout + (size_t)row * 512;
  const bf16* bp0 = btqkv + ((size_t)(nb*64 + (2*nh+0)*16 + lm)) * 512;
  const bf16* bp1 = btqkv + ((size_t)(nb*64 + (2*nh+1)*16 + lm)) * 512;
  #pragma unroll
  for (int kk = 0; kk < 16; ++kk){
    int kb = kk*32 + q*8;
    s8 A = ldg8(ap + kb);
    acc[0] = MFMA16(A, ldg8(bp0 + kb), acc[0]);
    acc[1] = MFMA16(A, ldg8(bp1 + kb), acc[1]);
  }
  #pragma unroll
  for (int i = 0; i < 2; ++i){
    int e = nb*64 + (2*nh+i)*16 + lm;
    float bias = biasq[e];
    #pragma unroll
    for (int r = 0; r < 4; ++r){
      int rr = rb*64 + mt*16 + q*4 + r;
      bf16 v = __float2bfloat16(acc[i][r] + bias);
      if (e < 512)        yq[(size_t)rr*512 + e] = v;
      else if (e < 1024)  yk[(size_t)rr*512 + (e-512)] = v;
      else {
        int d = e - 1024, hh = d >> 7, dh = d & 127;
        vt[((size_t)((rr >> 9)*4 + hh)*128 + dh)*512 + (rr & 511)] = v;
      }
    }
  }
}

// ================= K3: fused scores + softmax + PV -> decoded ============
// grid (8 rowblocks, 256 bh), 256 thr (4 waves, wave = 16-row Q tile).
// LDS: 64KiB union — sK[128][128] during scores, sP[64][512] (XOR-swizzled)
// for the P layout round-trip into the PV MFMA A-operand.
__global__ __launch_bounds__(256) void k3_attn(const bf16* yq, const bf16* yk, const bf16* vt,
                                               float* dec)
{
  int rb = blockIdx.x, bh = blockIdx.y;
  int b1 = bh >> 2, hh = bh & 3;
  int tid = threadIdx.x, w = tid >> 6, lane = tid & 63, lm = lane & 15, q = lane >> 4;
  __shared__ short sbuf[32768];             // 64KiB
  short (*sK)[128] = (short(*)[128])sbuf;   // 16384 shorts = 32KiB
  // A fragments (Q rows), K=128 -> 4 k-steps
  s8 Af[4];
  const bf16* apr = yq + ((size_t)(b1*512 + rb*64 + w*16 + lm))*512 + hh*128;
  #pragma unroll
  for (int kk = 0; kk < 4; ++kk) Af[kk] = ldg8(apr + kk*32 + q*8);
  f4 acc[32];
  #pragma unroll
  for (int nt = 0; nt < 32; ++nt) acc[nt] = (f4){0,0,0,0};

  for (int ch = 0; ch < 4; ++ch){
    __syncthreads();
    #pragma unroll
    for (int it = 0; it < 8; ++it){
      int lin = tid + it*256;              // 0..2047
      int srow = lin >> 4, seg = lin & 15; // 16 segs of 8 bf16
      int pseg = seg ^ (srow & 15);        // swizzle
      *(s8*)&sK[srow][pseg*8] =
        ldg8(yk + ((size_t)(b1*512 + ch*128 + srow))*512 + hh*128 + seg*8);
    }
    __syncthreads();
    #pragma unroll
    for (int ntl = 0; ntl < 8; ++ntl){
      int nt = ch*8 + ntl;
      int brow = ntl*16 + lm;
      #pragma unroll
      for (int kk = 0; kk < 4; ++kk){
        int c = (kk*4 + q) ^ lm;           // de-swizzle
        s8 Bfr = *(const s8*)&sK[brow][c*8];
        acc[nt] = MFMA16(Af[kk], Bfr, acc[nt]);
      }
    }
  }
  // softmax over the full 512-col row (16 lanes x 32 n-tiles)
  const float scale = 0.08838834764831845f;  // 1/sqrt(128)
  float mx[4], sm[4];
  #pragma unroll
  for (int r = 0; r < 4; ++r){
    float m = -1e30f;
    #pragma unroll
    for (int nt = 0; nt < 32; ++nt) m = fmaxf(m, acc[nt][r]);
    mx[r] = m;
  }
  #pragma unroll
  for (int d = 1; d < 16; d <<= 1){
    #pragma unroll
    for (int r = 0; r < 4; ++r) mx[r] = fmaxf(mx[r], __shfl_xor(mx[r], d, 64));
  }
  #pragma unroll
  for (int r = 0; r < 4; ++r){
    float s = 0.f;
    #pragma unroll
    for (int nt = 0; nt < 32; ++nt){
      float e = __expf(scale * (acc[nt][r] - mx[r]));
      acc[nt][r] = e; s += e;
    }
    sm[r] = s;
  }
  #pragma unroll
  for (int d = 1; d < 16; d <<= 1){
    #pragma unroll
    for (int r = 0; r < 4; ++r) sm[r] += __shfl_xor(sm[r], d, 64);
  }
  float inv[4];
  #pragma unroll
  for (int r = 0; r < 4; ++r) inv[r] = 1.f / sm[r];

  __syncthreads();   // all sK reads done before sP overwrites the buffer
  // P tile -> LDS, XOR-swizzled 16B chunks: phys = row*512 + ((col>>3)^(row&15))*8 + (col&7)
  #pragma unroll
  for (int nt = 0; nt < 32; ++nt){
    #pragma unroll
    for (int r = 0; r < 4; ++r){
      int rowp = w*16 + q*4 + r, col = nt*16 + lm;
      sbuf[rowp*512 + (((col >> 3) ^ (rowp & 15))*8) + (col & 7)] =
        f2bs(acc[nt][r] * inv[r]);
    }
  }
  // PV: wave-local (each wave reads only rows it wrote) — no barrier needed
  f4 o[8];
  #pragma unroll
  for (int n2 = 0; n2 < 8; ++n2) o[n2] = (f4){0,0,0,0};
  int rowa = w*16 + lm;
  #pragma unroll
  for (int kk = 0; kk < 16; ++kk){
    s8 A = *(const s8*)&sbuf[rowa*512 + (((kk*4 + q) ^ (rowa & 15))*8)];
    #pragma unroll
    for (int n2 = 0; n2 < 8; ++n2){
      s8 Bfr = ldg8(vt + ((size_t)(bh*128 + n2*16 + lm))*512 + kk*32 + q*8);
      o[n2] = MFMA16(A, Bfr, o[n2]);
    }
  }
  #pragma unroll
  for (int n2 = 0; n2 < 8; ++n2){
    int d = n2*16 + lm;
    #pragma unroll
    for (int r = 0; r < 4; ++r){
      int s1 = rb*64 + w*16 + q*4 + r;
      dec[((size_t)s1*64 + b1)*512 + hh*128 + d] = o[n2][r];
    }
  }
}

// ================= launcher =================
extern "C" void kernel_launch(void* const* d_in, const int* in_sizes, int n_in,
                              void* d_out, int out_size, void* d_ws, size_t ws_size,
                              hipStream_t stream)
{
  const float* x   = (const float*)d_in[0];
  const float* Wf  = (const float*)d_in[1];  const float* bfv = (const float*)d_in[2];
  const float* Wi  = (const float*)d_in[3];  const float* biv = (const float*)d_in[4];
  const float* Wg  = (const float*)d_in[5];  const float* bgv = (const float*)d_in[6];
  const float* Wo  = (const float*)d_in[7];  const float* bov = (const float*)d_in[8];
  const float* Wq  = (const float*)d_in[9];  const float* bqv = (const float*)d_in[10];
  const float* Wk  = (const float*)d_in[11]; const float* bkv = (const float*)d_in[12];
  const float* Wv  = (const float*)d_in[13]; const float* bvv = (const float*)d_in[14];

  char* ws = (char*)d_ws;
  int*   flags = (int*)  (ws + OF_FLAGS);
  float* bias4 = (float*)(ws + OF_BIAS4);
  float* biasq = (float*)(ws + OF_BIASQ);
  int*   claim = (int*)  (ws + OF_CLAIM);
  bf16*  btx   = (bf16*) (ws + OF_BTX);
  bf16*  bth   = (bf16*) (ws + OF_BTH);
  bf16*  btqkv = (bf16*) (ws + OF_BTQKV);
  bf16*  yq    = (bf16*) (ws + OF_YQ);
  bf16*  yk    = (bf16*) (ws + OF_YK);
  bf16*  vt    = (bf16*) (ws + OF_VT);

  char* outc = (char*)d_out;
  bf16*  lout = (bf16*)(outc + DOUT_LOUT);   // dead before decode writes
  bf16*  xbf  = (bf16*)(outc + DOUT_XBF);    // dead before decode writes
  float* out  = (float*)d_out;

  hipLaunchKernelGGL(k0_pack, dim3(2048), dim3(256), 0, stream,
                     x, Wf, Wi, Wg, Wo, bfv, biv, bgv, bov, Wq, Wk, Wv, bqv, bkv, bvv,
                     xbf, btx, bth, btqkv, bias4, biasq, flags, claim);
  hipLaunchKernelGGL(k1_lstm, dim3(512), dim3(512), 0, stream,
                     xbf, btx, bth, bias4, lout, flags, claim, out + DEC_SZ);
  hipLaunchKernelGGL(k2_qkv, dim3(24, 512), dim3(512), 0, stream, lout, btqkv, biasq, yq, yk, vt);
  hipLaunchKernelGGL(k3_attn, dim3(8, 256), dim3(256), 0, stream, yq, yk, vt, out);
}

// Round 7
// 4348.221 us; speedup vs baseline: 1.1745x; 1.0047x over previous
//
#include <hip/hip_runtime.h>
#include <hip/hip_bf16.h>

typedef __attribute__((ext_vector_type(8))) short s8;
typedef __attribute__((ext_vector_type(4))) float f4;

using bf16 = __hip_bfloat16;

#define MFMA16(a,b,c) __builtin_amdgcn_mfma_f32_16x16x32_bf16((a),(b),(c),0,0,0)

// HW_REG_XCC_ID (id=20), offset 0, width 4  ->  simm16 = id | (off<<6) | ((w-1)<<11)
#define GETREG_XCC_ID (20 | (0 << 6) | (3 << 11))

// ---------------- sizes ----------------
constexpr int SS = 512, BBATCH = 64, HIDN = 512;
constexpr size_t DEC_SZ = (size_t)SS * BBATCH * HIDN;  // 16777216 f32 = 64MiB

// ---------------- ws layout (bytes), total 101 MiB ----------------
constexpr size_t OF_FLAGS = 0;                  // 512*32*4 = 64KiB (one 128B line per step)
constexpr size_t OF_BIAS4 = 65536;              // 2048 f32
constexpr size_t OF_BIASQ = 73728;              // 1536 f32  (ends 79872)
constexpr size_t OF_CLAIM = 81920;              // int[0]=worker-slot counter; int[32]=done
constexpr size_t OF_BTX   = 131072;             // Bt_x [2048][256] bf16 = 1MiB
constexpr size_t OF_BTH   = 1179648;            // Bt_h [2048][512] bf16 = 2MiB
constexpr size_t OF_BTQKV = 3276800;            // Bt_qkv [1536][512] bf16 = 1.5MiB
constexpr size_t OF_YQ    = (size_t)5  << 20;   // 32MiB
constexpr size_t OF_YK    = OF_YQ + ((size_t)32 << 20);
constexpr size_t OF_VT    = OF_YK + ((size_t)32 << 20);   // ends at 101MiB

// d_out scratch offsets (inside 64MiB decoded region; dead before decode writes)
constexpr size_t DOUT_LOUT = 0;                 // lout bf16 [32768][512] = 32MiB
constexpr size_t DOUT_XBF  = (size_t)32 << 20;  // xbf bf16 [32768][256] = 16MiB

// ---------------- helpers ----------------
__device__ inline s8 ldg8(const bf16* p){ return *(const s8*)p; }
__device__ inline short f2bs(float f){ return __builtin_bit_cast(short, __float2bfloat16(f)); }
__device__ inline float sigf(float x){ return 1.f/(1.f + __expf(-x)); }
__device__ inline float tanhf_(float x){ x = fminf(fmaxf(x, -15.f), 15.f); float e = __expf(2.f*x); return (e-1.f)/(e+1.f); }

// ================= K0: pack weights/biases/x, zero flags =================
__global__ void k0_pack(const float* x,
                        const float* Wf,const float* Wi,const float* Wg,const float* Wo,
                        const float* bfv,const float* biv,const float* bgv,const float* bov,
                        const float* Wq,const float* Wk,const float* Wv,
                        const float* bqv,const float* bkv,const float* bvv,
                        bf16* xbf, bf16* btx, bf16* bth, bf16* btqkv,
                        float* bias4, float* biasq, int* flags, int* claim)
{
  const float* WG[4] = {Wf, Wi, Wg, Wo};
  const float* BG[4] = {bfv, biv, bgv, bov};
  const float* WQ[3] = {Wq, Wk, Wv};
  const float* BQ[3] = {bqv, bkv, bvv};
  const long NX   = 8388608;   // 32768*256
  const long NBTH = 1048576;   // 2048*512
  const long NBTQ = 786432;    // 1536*512
  const long NBTX = 524288;    // 2048*256
  const long NF   = 16384;     // 512*32
  const long TOT  = NX + NBTH + NBTQ + NBTX + NF + 2048 + 1536 + 1;
  long stride = (long)gridDim.x * blockDim.x;
  for (long i = (long)blockIdx.x*blockDim.x + threadIdx.x; i < TOT; i += stride){
    if (i < NX){ xbf[i] = __float2bfloat16(x[i]); }
    else if (i < NX + NBTH){
      long j = i - NX; int n = (int)(j >> 9), k = (int)(j & 511);
      int g = n >> 9, hid = n & 511;
      bth[j] = __float2bfloat16(WG[g][(size_t)(256 + k)*512 + hid]);
    } else if (i < NX + NBTH + NBTQ){
      long j = i - NX - NBTH; int n = (int)(j >> 9), k = (int)(j & 511);
      int w = n >> 9, c = n & 511;
      btqkv[j] = __float2bfloat16(WQ[w][(size_t)k*512 + c]);
    } else if (i < NX + NBTH + NBTQ + NBTX){
      long j = i - NX - NBTH - NBTQ; int n = (int)(j >> 8), k = (int)(j & 255);
      int g = n >> 9, hid = n & 511;
      btx[j] = __float2bfloat16(WG[g][(size_t)k*512 + hid]);
    } else if (i < NX + NBTH + NBTQ + NBTX + NF){
      flags[i - NX - NBTH - NBTQ - NBTX] = 0;
    } else if (i < NX + NBTH + NBTQ + NBTX + NF + 2048){
      long j = i - NX - NBTH - NBTQ - NBTX - NF; int g = (int)(j >> 9), hid = (int)(j & 511);
      bias4[j] = BG[g][hid];
    } else if (i < NX + NBTH + NBTQ + NBTX + NF + 2048 + 1536){
      long j = i - NX - NBTH - NBTQ - NBTX - NF - 2048; int w = (int)(j >> 9), c = (int)(j & 511);
      biasq[j] = BQ[w][c];
    } else {
      claim[0] = 0;    // worker-slot counter
      claim[32] = 0;   // done flag (own 128B line)
    }
  }
}

// ================= K1: persistent LSTM recurrence, XCD0-pinned ===========
// 512 blocks launched (2 per CU, all co-resident). First 32 blocks landing
// on XCD 0 claim worker slots and run the EXACT round-2/6 recurrence
// (3858-3870us proven). All OTHER 480 blocks become HEATERS.
//
// DVFS theory (round-7): steady-state k1 presents ~1% VALU/MFMA activity on
// 32 of 256 CUs -> the SMU's activity-based governor drops the GFX clock to
// ~500MHz, inflating every latency segment ~4-5x. Evidence: 7.56us/step =
// ~3800cy @500MHz matches the bottom-up serial-latency model exactly;
// r1's slow-load delta (+2us/step) and r4's extra-barrier delta (+2us/step)
// both fit ~1000cy @500MHz; r6's in-poll spin never executed (VALUBusy
// 1.3%) because waves arrive at the poll already stalled.
// Fix: heaters run dependent-FMA chains at full VALU duty on every CU's
// otherwise-idle 2nd block slot (including XCD0's surplus blocks, in case
// clocking is per-XCD), holding chip activity high for the whole recurrence.
// Heaters exit when workers set done (claim[32]); bounded by iteration cap.
__global__ __launch_bounds__(512) void k1_lstm(const bf16* xbf, const bf16* btx, const bf16* bth,
                                               const float* bias4, bf16* lout, int* flags,
                                               int* claim, float* out_tail)
{
  __shared__ int s_ns;
  int xcc = (int)(__builtin_amdgcn_s_getreg(GETREG_XCC_ID) & 15);
  if (threadIdx.x == 0){
    int nsl = -1;
    if (xcc == 0){
      nsl = __hip_atomic_fetch_add(claim, 1, __ATOMIC_RELAXED, __HIP_MEMORY_SCOPE_AGENT);
      if (nsl >= 32) nsl = -1;
    }
    s_ns = nsl;
  }
  __syncthreads();
  int ns = s_ns;
  int* done = claim + 32;

  if (ns < 0){
    // ---------------- heater ----------------
    float h0 = (float)threadIdx.x * 0.001f + 1.0f;
    float h1 = h0 + 0.25f, h2 = h0 + 0.5f, h3 = h0 + 0.75f;
    for (int it = 0; it < (1 << 13); ++it){        // cap ~65-260ms (loud, bounded)
      #pragma unroll 16
      for (int u = 0; u < 2048; ++u){              // 8192 dependent-ish FMAs (4 chains)
        h0 = __builtin_fmaf(h0, 1.0000001f, 1e-7f);
        h1 = __builtin_fmaf(h1, 1.0000001f, 2e-7f);
        h2 = __builtin_fmaf(h2, 1.0000002f, 3e-7f);
        h3 = __builtin_fmaf(h3, 1.0000002f, 4e-7f);
      }
      asm volatile("" :: "v"(h0), "v"(h1), "v"(h2), "v"(h3));
      int d = __hip_atomic_load(done, __ATOMIC_RELAXED, __HIP_MEMORY_SCOPE_AGENT);
      if (d != 0) break;
    }
    return;
  }

  // ---------------- worker (exact round-2/6 structure) ----------------
  int tid = threadIdx.x, w = tid >> 6, lane = tid & 63;
  int mt = w >> 1, nh = w & 1, lm = lane & 15, q = lane >> 4;
  __shared__ float pre[64][68];

  // resident B-fragments: 2 gates (2*nh, 2*nh+1)
  s8 Bh[2][16], Bx[2][8];
  #pragma unroll
  for (int i = 0; i < 2; ++i){
    const bf16* bph = bth + ((size_t)((2*nh+i)*512 + ns*16 + lm)) * 512;
    #pragma unroll
    for (int kk = 0; kk < 16; ++kk) Bh[i][kk] = ldg8(bph + kk*32 + q*8);
    const bf16* bpx = btx + ((size_t)((2*nh+i)*512 + ns*16 + lm)) * 256;
    #pragma unroll
    for (int kk = 0; kk < 8; ++kk) Bx[i][kk] = ldg8(bpx + kk*32 + q*8);
  }
  // elementwise cells: thread owns (b0, j0) and (b0, j0+1)
  int c0 = 2*tid, b0 = c0 >> 4, j0 = c0 & 15;
  float bs[8];
  #pragma unroll
  for (int g = 0; g < 4; ++g){
    bs[g]   = bias4[g*512 + ns*16 + j0];
    bs[4+g] = bias4[g*512 + ns*16 + j0 + 1];
  }
  float cs0 = 0.f, cs1 = 0.f;
  int budget = 1 << 22;   // poll bailout (loud failure, bounded)

  for (int t = 0; t < 512; ++t){
    // x-part GEMM (independent of recurrence -> before the poll)
    f4 acc0 = {0,0,0,0}, acc1 = {0,0,0,0};
    const bf16* xr = xbf + ((size_t)(t*64 + mt*16 + lm)) * 256;
    #pragma unroll
    for (int kk = 0; kk < 8; ++kk){
      s8 A = ldg8(xr + kk*32 + q*8);
      acc0 = MFMA16(A, Bx[0][kk], acc0);
      acc1 = MFMA16(A, Bx[1][kk], acc1);
    }
    if (t > 0){
      const int* fp = flags + (size_t)(t-1)*32 + (lane & 31);
      while (budget > 0){
        int v;
        asm volatile("global_load_dword %0, %1, off sc0\n\ts_waitcnt vmcnt(0)"
                     : "=v"(v) : "v"(fp) : "memory");
        if (__ballot(v != 0) == ~0ull) break;
        budget--;
        __builtin_amdgcn_s_sleep(1);
      }
      // compiler reorder barrier only; no cache maintenance needed (same-XCD L2)
      __builtin_amdgcn_fence(__ATOMIC_ACQUIRE, "workgroup");
      const bf16* hr = lout + ((size_t)((t-1)*64 + mt*16 + lm)) * 512;
      #pragma unroll
      for (int kk = 0; kk < 16; ++kk){
        s8 Ah = ldg8(hr + kk*32 + q*8);
        acc0 = MFMA16(Ah, Bh[0][kk], acc0);
        acc1 = MFMA16(Ah, Bh[1][kk], acc1);
      }
    }
    // pre-activations -> LDS
    #pragma unroll
    for (int i = 0; i < 2; ++i){
      int col = (2*nh+i)*16 + lm;
      f4 av = (i == 0) ? acc0 : acc1;
      #pragma unroll
      for (int r = 0; r < 4; ++r) pre[mt*16 + q*4 + r][col] = av[r];
    }
    __syncthreads();
    // elementwise gates for 2 cells
    {
      float fh0 = pre[b0][ 0+j0] + bs[0], fh1 = pre[b0][ 0+j0+1] + bs[4];
      float ih0 = pre[b0][16+j0] + bs[1], ih1 = pre[b0][16+j0+1] + bs[5];
      float gh0 = pre[b0][32+j0] + bs[2], gh1 = pre[b0][32+j0+1] + bs[6];
      float oh0 = pre[b0][48+j0] + bs[3], oh1 = pre[b0][48+j0+1] + bs[7];
      cs0 = sigf(fh0)*cs0 + sigf(ih0)*tanhf_(gh0);
      cs1 = sigf(fh1)*cs1 + sigf(ih1)*tanhf_(gh1);
      float h0v = sigf(oh0)*tanhf_(cs0);
      float h1v = sigf(oh1)*tanhf_(cs1);
      unsigned hv = (unsigned)(unsigned short)f2bs(h0v) | ((unsigned)(unsigned short)f2bs(h1v) << 16);
      // plain store: write-through L1 -> lands in XCD0 L2 (the sync domain)
      *(unsigned*)(lout + ((size_t)(t*64 + b0))*512 + ns*16 + j0) = hv;
      if (t == 511){
        float* hx = out_tail + (size_t)b0*512 + ns*16 + j0;
        hx[0] = h0v; hx[1] = h1v;
        float* cx = out_tail + 32768 + (size_t)b0*512 + ns*16 + j0;
        cx[0] = cs0; cx[1] = cs1;
      }
    }
    __syncthreads();   // implies vmcnt(0): all h stores drained to L2
    if (tid == 0)
      *(volatile int*)(flags + (size_t)t*32 + ns) = 1;
  }
  // release the heaters
  if (tid == 0)
    __hip_atomic_store(done, 1, __ATOMIC_RELAXED, __HIP_MEMORY_SCOPE_AGENT);
}

// ================= K2: fused QKV GEMM (N=1536), V written transposed =====
// grid (24, 512), 512 thr. Tile 64x64, K=512.
__global__ __launch_bounds__(512) void k2_qkv(const bf16* lout, const bf16* btqkv, const float* biasq,
                                              bf16* yq, bf16* yk, bf16* vt)
{
  int nb = blockIdx.x, rb = blockIdx.y;
  int tid = threadIdx.x, w = tid >> 6, lane = tid & 63;
  int mt = w >> 1, nh = w & 1, lm = lane & 15, q = lane >> 4;
  int row = rb*64 + mt*16 + lm;
  f4 acc[2] = {{0,0,0,0},{0,0,0,0}};
  const bf16* ap  = lout + (size_t)row * 512;
  const bf16* bp0 = btqkv + ((size_t)(nb*64 + (2*nh+0)*16 + lm)) * 512;
  const bf16* bp1 = btqkv + ((size_t)(nb*64 + (2*nh+1)*16 + lm)) * 512;
  #pragma unroll
  for (int kk = 0; kk < 16; ++kk){
    int kb = kk*32 + q*8;
    s8 A = ldg8(ap + kb);
    acc[0] = MFMA16(A, ldg8(bp0 + kb), acc[0]);
    acc[1] = MFMA16(A, ldg8(bp1 + kb), acc[1]);
  }
  #pragma unroll
  for (int i = 0; i < 2; ++i){
    int e = nb*64 + (2*nh+i)*16 + lm;
    float bias = biasq[e];
    #pragma unroll
    for (int r = 0; r < 4; ++r){
      int rr = rb*64 + mt*16 + q*4 + r;
      bf16 v = __float2bfloat16(acc[i][r] + bias);
      if (e < 512)        yq[(size_t)rr*512 + e] = v;
      else if (e < 1024)  yk[(size_t)rr*512 + (e-512)] = v;
      else {
        int d = e - 1024, hh = d >> 7, dh = d & 127;
        vt[((size_t)((rr >> 9)*4 + hh)*128 + dh)*512 + (rr & 511)] = v;
      }
    }
  }
}

// ================= K3: fused scores + softmax + PV -> decoded ============
// grid (8 rowblocks, 256 bh), 256 thr (4 waves, wave = 16-row Q tile).
// LDS: 64KiB union — sK[128][128] during scores, sP[64][512] (XOR-swizzled)
// for the P layout round-trip into the PV MFMA A-operand.
__global__ __launch_bounds__(256) void k3_attn(const bf16* yq, const bf16* yk, const bf16* vt,
                                               float* dec)
{
  int rb = blockIdx.x, bh = blockIdx.y;
  int b1 = bh >> 2, hh = bh & 3;
  int tid = threadIdx.x, w = tid >> 6, lane = tid & 63, lm = lane & 15, q = lane >> 4;
  __shared__ short sbuf[32768];             // 64KiB
  short (*sK)[128] = (short(*)[128])sbuf;   // 16384 shorts = 32KiB
  // A fragments (Q rows), K=128 -> 4 k-steps
  s8 Af[4];
  const bf16* apr = yq + ((size_t)(b1*512 + rb*64 + w*16 + lm))*512 + hh*128;
  #pragma unroll
  for (int kk = 0; kk < 4; ++kk) Af[kk] = ldg8(apr + kk*32 + q*8);
  f4 acc[32];
  #pragma unroll
  for (int nt = 0; nt < 32; ++nt) acc[nt] = (f4){0,0,0,0};

  for (int ch = 0; ch < 4; ++ch){
    __syncthreads();
    #pragma unroll
    for (int it = 0; it < 8; ++it){
      int lin = tid + it*256;              // 0..2047
      int srow = lin >> 4, seg = lin & 15; // 16 segs of 8 bf16
      int pseg = seg ^ (srow & 15);        // swizzle
      *(s8*)&sK[srow][pseg*8] =
        ldg8(yk + ((size_t)(b1*512 + ch*128 + srow))*512 + hh*128 + seg*8);
    }
    __syncthreads();
    #pragma unroll
    for (int ntl = 0; ntl < 8; ++ntl){
      int nt = ch*8 + ntl;
      int brow = ntl*16 + lm;
      #pragma unroll
      for (int kk = 0; kk < 4; ++kk){
        int c = (kk*4 + q) ^ lm;           // de-swizzle
        s8 Bfr = *(const s8*)&sK[brow][c*8];
        acc[nt] = MFMA16(Af[kk], Bfr, acc[nt]);
      }
    }
  }
  // softmax over the full 512-col row (16 lanes x 32 n-tiles)
  const float scale = 0.08838834764831845f;  // 1/sqrt(128)
  float mx[4], sm[4];
  #pragma unroll
  for (int r = 0; r < 4; ++r){
    float m = -1e30f;
    #pragma unroll
    for (int nt = 0; nt < 32; ++nt) m = fmaxf(m, acc[nt][r]);
    mx[r] = m;
  }
  #pragma unroll
  for (int d = 1; d < 16; d <<= 1){
    #pragma unroll
    for (int r = 0; r < 4; ++r) mx[r] = fmaxf(mx[r], __shfl_xor(mx[r], d, 64));
  }
  #pragma unroll
  for (int r = 0; r < 4; ++r){
    float s = 0.f;
    #pragma unroll
    for (int nt = 0; nt < 32; ++nt){
      float e = __expf(scale * (acc[nt][r] - mx[r]));
      acc[nt][r] = e; s += e;
    }
    sm[r] = s;
  }
  #pragma unroll
  for (int d = 1; d < 16; d <<= 1){
    #pragma unroll
    for (int r = 0; r < 4; ++r) sm[r] += __shfl_xor(sm[r], d, 64);
  }
  float inv[4];
  #pragma unroll
  for (int r = 0; r < 4; ++r) inv[r] = 1.f / sm[r];

  __syncthreads();   // all sK reads done before sP overwrites the buffer
  // P tile -> LDS, XOR-swizzled 16B chunks: phys = row*512 + ((col>>3)^(row&15))*8 + (col&7)
  #pragma unroll
  for (int nt = 0; nt < 32; ++nt){
    #pragma unroll
    for (int r = 0; r < 4; ++r){
      int rowp = w*16 + q*4 + r, col = nt*16 + lm;
      sbuf[rowp*512 + (((col >> 3) ^ (rowp & 15))*8) + (col & 7)] =
        f2bs(acc[nt][r] * inv[r]);
    }
  }
  // PV: wave-local (each wave reads only rows it wrote) — no barrier needed
  f4 o[8];
  #pragma unroll
  for (int n2 = 0; n2 < 8; ++n2) o[n2] = (f4){0,0,0,0};
  int rowa = w*16 + lm;
  #pragma unroll
  for (int kk = 0; kk < 16; ++kk){
    s8 A = *(const s8*)&sbuf[rowa*512 + (((kk*4 + q) ^ (rowa & 15))*8)];
    #pragma unroll
    for (int n2 = 0; n2 < 8; ++n2){
      s8 Bfr = ldg8(vt + ((size_t)(bh*128 + n2*16 + lm))*512 + kk*32 + q*8);
      o[n2] = MFMA16(A, Bfr, o[n2]);
    }
  }
  #pragma unroll
  for (int n2 = 0; n2 < 8; ++n2){
    int d = n2*16 + lm;
    #pragma unroll
    for (int r = 0; r < 4; ++r){
      int s1 = rb*64 + w*16 + q*4 + r;
      dec[((size_t)s1*64 + b1)*512 + hh*128 + d] = o[n2][r];
    }
  }
}

// ================= launcher =================
extern "C" void kernel_launch(void* const* d_in, const int* in_sizes, int n_in,
                              void* d_out, int out_size, void* d_ws, size_t ws_size,
                              hipStream_t stream)
{
  const float* x   = (const float*)d_in[0];
  const float* Wf  = (const float*)d_in[1];  const float* bfv = (const float*)d_in[2];
  const float* Wi  = (const float*)d_in[3];  const float* biv = (const float*)d_in[4];
  const float* Wg  = (const float*)d_in[5];  const float* bgv = (const float*)d_in[6];
  const float* Wo  = (const float*)d_in[7];  const float* bov = (const float*)d_in[8];
  const float* Wq  = (const float*)d_in[9];  const float* bqv = (const float*)d_in[10];
  const float* Wk  = (const float*)d_in[11]; const float* bkv = (const float*)d_in[12];
  const float* Wv  = (const float*)d_in[13]; const float* bvv = (const float*)d_in[14];

  char* ws = (char*)d_ws;
  int*   flags = (int*)  (ws + OF_FLAGS);
  float* bias4 = (float*)(ws + OF_BIAS4);
  float* biasq = (float*)(ws + OF_BIASQ);
  int*   claim = (int*)  (ws + OF_CLAIM);
  bf16*  btx   = (bf16*) (ws + OF_BTX);
  bf16*  bth   = (bf16*) (ws + OF_BTH);
  bf16*  btqkv = (bf16*) (ws + OF_BTQKV);
  bf16*  yq    = (bf16*) (ws + OF_YQ);
  bf16*  yk    = (bf16*) (ws + OF_YK);
  bf16*  vt    = (bf16*) (ws + OF_VT);

  char* outc = (char*)d_out;
  bf16*  lout = (bf16*)(outc + DOUT_LOUT);   // dead before decode writes
  bf16*  xbf  = (bf16*)(outc + DOUT_XBF);    // dead before decode writes
  float* out  = (float*)d_out;

  hipLaunchKernelGGL(k0_pack, dim3(2048), dim3(256), 0, stream,
                     x, Wf, Wi, Wg, Wo, bfv, biv, bgv, bov, Wq, Wk, Wv, bqv, bkv, bvv,
                     xbf, btx, bth, btqkv, bias4, biasq, flags, claim);
  hipLaunchKernelGGL(k1_lstm, dim3(512), dim3(512), 0, stream,
                     xbf, btx, bth, bias4, lout, flags, claim, out + DEC_SZ);
  hipLaunchKernelGGL(k2_qkv, dim3(24, 512), dim3(512), 0, stream, lout, btqkv, biasq, yq, yk, vt);
  hipLaunchKernelGGL(k3_attn, dim3(8, 256), dim3(256), 0, stream, yq, yk, vt, out);
}

// Round 8
// 4325.500 us; speedup vs baseline: 1.1807x; 1.0053x over previous
//
#include <hip/hip_runtime.h>
#include <hip/hip_bf16.h>

typedef __attribute__((ext_vector_type(8))) short s8;
typedef __attribute__((ext_vector_type(4))) float f4;

using bf16 = __hip_bfloat16;

#define MFMA16(a,b,c) __builtin_amdgcn_mfma_f32_16x16x32_bf16((a),(b),(c),0,0,0)

// HW_REG_XCC_ID (id=20), offset 0, width 4  ->  simm16 = id | (off<<6) | ((w-1)<<11)
#define GETREG_XCC_ID (20 | (0 << 6) | (3 << 11))

// ---------------- sizes ----------------
constexpr int SS = 512, BBATCH = 64, HIDN = 512;
constexpr size_t DEC_SZ = (size_t)SS * BBATCH * HIDN;  // 16777216 f32 = 64MiB

// ---------------- ws layout (bytes), total 101 MiB ----------------
constexpr size_t OF_FLAGS = 0;                  // 512*32*4 = 64KiB (one 128B line per step)
constexpr size_t OF_BIAS4 = 65536;              // 2048 f32
constexpr size_t OF_BIASQ = 73728;              // 1536 f32  (ends 79872)
constexpr size_t OF_CLAIM = 81920;              // int[0]=worker-slot counter
constexpr size_t OF_BTX   = 131072;             // Bt_x [2048][256] bf16 = 1MiB
constexpr size_t OF_BTH   = 1179648;            // Bt_h [2048][512] bf16 = 2MiB
constexpr size_t OF_BTQKV = 3276800;            // Bt_qkv [1536][512] bf16 = 1.5MiB
constexpr size_t OF_YQ    = (size_t)5  << 20;   // 32MiB
constexpr size_t OF_YK    = OF_YQ + ((size_t)32 << 20);
constexpr size_t OF_VT    = OF_YK + ((size_t)32 << 20);   // ends at 101MiB

// d_out scratch offsets (inside 64MiB decoded region; dead before decode writes)
constexpr size_t DOUT_LOUT = 0;                 // lout bf16 [32768][512] = 32MiB
constexpr size_t DOUT_XBF  = (size_t)32 << 20;  // xbf bf16 [32768][256] = 16MiB

// ---------------- helpers ----------------
__device__ inline s8 ldg8(const bf16* p){ return *(const s8*)p; }
__device__ inline short f2bs(float f){ return __builtin_bit_cast(short, __float2bfloat16(f)); }
__device__ inline float sigf(float x){ return 1.f/(1.f + __expf(-x)); }
__device__ inline float tanhf_(float x){ x = fminf(fmaxf(x, -15.f), 15.f); float e = __expf(2.f*x); return (e-1.f)/(e+1.f); }

// ================= K0: pack weights/biases/x, zero flags =================
__global__ void k0_pack(const float* x,
                        const float* Wf,const float* Wi,const float* Wg,const float* Wo,
                        const float* bfv,const float* biv,const float* bgv,const float* bov,
                        const float* Wq,const float* Wk,const float* Wv,
                        const float* bqv,const float* bkv,const float* bvv,
                        bf16* xbf, bf16* btx, bf16* bth, bf16* btqkv,
                        float* bias4, float* biasq, int* flags, int* claim)
{
  const float* WG[4] = {Wf, Wi, Wg, Wo};
  const float* BG[4] = {bfv, biv, bgv, bov};
  const float* WQ[3] = {Wq, Wk, Wv};
  const float* BQ[3] = {bqv, bkv, bvv};
  const long NX   = 8388608;   // 32768*256
  const long NBTH = 1048576;   // 2048*512
  const long NBTQ = 786432;    // 1536*512
  const long NBTX = 524288;    // 2048*256
  const long NF   = 16384;     // 512*32
  const long TOT  = NX + NBTH + NBTQ + NBTX + NF + 2048 + 1536 + 1;
  long stride = (long)gridDim.x * blockDim.x;
  for (long i = (long)blockIdx.x*blockDim.x + threadIdx.x; i < TOT; i += stride){
    if (i < NX){ xbf[i] = __float2bfloat16(x[i]); }
    else if (i < NX + NBTH){
      long j = i - NX; int n = (int)(j >> 9), k = (int)(j & 511);
      int g = n >> 9, hid = n & 511;
      bth[j] = __float2bfloat16(WG[g][(size_t)(256 + k)*512 + hid]);
    } else if (i < NX + NBTH + NBTQ){
      long j = i - NX - NBTH; int n = (int)(j >> 9), k = (int)(j & 511);
      int w = n >> 9, c = n & 511;
      btqkv[j] = __float2bfloat16(WQ[w][(size_t)k*512 + c]);
    } else if (i < NX + NBTH + NBTQ + NBTX){
      long j = i - NX - NBTH - NBTQ; int n = (int)(j >> 8), k = (int)(j & 255);
      int g = n >> 9, hid = n & 511;
      btx[j] = __float2bfloat16(WG[g][(size_t)k*512 + hid]);
    } else if (i < NX + NBTH + NBTQ + NBTX + NF){
      flags[i - NX - NBTH - NBTQ - NBTX] = 0;
    } else if (i < NX + NBTH + NBTQ + NBTX + NF + 2048){
      long j = i - NX - NBTH - NBTQ - NBTX - NF; int g = (int)(j >> 9), hid = (int)(j & 511);
      bias4[j] = BG[g][hid];
    } else if (i < NX + NBTH + NBTQ + NBTX + NF + 2048 + 1536){
      long j = i - NX - NBTH - NBTQ - NBTX - NF - 2048; int w = (int)(j >> 9), c = (int)(j & 511);
      biasq[j] = BQ[w][c];
    } else {
      claim[0] = 0;    // worker-slot counter
    }
  }
}

// ================= K1: persistent LSTM recurrence, XCD0-pinned ===========
// 512 blocks launched; first 32 blocks landing on XCD 0 claim worker slots;
// all others exit. All cross-block traffic stays inside XCD0's 4MiB L2.
//
// Round-8 theory: all previous rounds ran at VGPR_Count=120-128, but the
// resident weight fragments need 192 VGPRs (Bh 2x16 s8 =128, Bx 2x8 s8 =64).
// The allocator (capped at 128 by the 2-blocks/CU default occupancy target)
// REMATERIALIZED ~23 weight-fragment loads per thread per STEP inside the
// MFMA loop. Per-block weight working set = 96KiB > 32KiB L1 -> every step,
// every wave re-pulls ~368B/lane of weights from L2 (~250-400cy), serialized
// against the dependent MFMAs: ~12k cy/step — the 6us/step no memory-
// protocol change could touch (r0-r7 all noise/neutral, as observed).
// Fix: __launch_bounds__(512, 2) -> 1 block/CU -> 256-VGPR budget ->
// weights genuinely register-resident. Smoking gun: VGPR_Count >= ~230.
__global__ __launch_bounds__(512, 2) void k1_lstm(const bf16* xbf, const bf16* btx, const bf16* bth,
                                                  const float* bias4, bf16* lout, int* flags,
                                                  int* claim, float* out_tail)
{
  __shared__ int s_ns;
  int xcc = (int)(__builtin_amdgcn_s_getreg(GETREG_XCC_ID) & 15);
  if (threadIdx.x == 0){
    int nsl = -1;
    if (xcc == 0){
      nsl = __hip_atomic_fetch_add(claim, 1, __ATOMIC_RELAXED, __HIP_MEMORY_SCOPE_AGENT);
      if (nsl >= 32) nsl = -1;
    }
    s_ns = nsl;
  }
  __syncthreads();
  int ns = s_ns;
  if (ns < 0) return;

  int tid = threadIdx.x, w = tid >> 6, lane = tid & 63;
  int mt = w >> 1, nh = w & 1, lm = lane & 15, q = lane >> 4;
  __shared__ float pre[64][68];

  // resident B-fragments: 2 gates (2*nh, 2*nh+1) — 192 VGPRs, now in budget
  s8 Bh[2][16], Bx[2][8];
  #pragma unroll
  for (int i = 0; i < 2; ++i){
    const bf16* bph = bth + ((size_t)((2*nh+i)*512 + ns*16 + lm)) * 512;
    #pragma unroll
    for (int kk = 0; kk < 16; ++kk) Bh[i][kk] = ldg8(bph + kk*32 + q*8);
    const bf16* bpx = btx + ((size_t)((2*nh+i)*512 + ns*16 + lm)) * 256;
    #pragma unroll
    for (int kk = 0; kk < 8; ++kk) Bx[i][kk] = ldg8(bpx + kk*32 + q*8);
  }
  // elementwise cells: thread owns (b0, j0) and (b0, j0+1)
  int c0 = 2*tid, b0 = c0 >> 4, j0 = c0 & 15;
  float bs[8];
  #pragma unroll
  for (int g = 0; g < 4; ++g){
    bs[g]   = bias4[g*512 + ns*16 + j0];
    bs[4+g] = bias4[g*512 + ns*16 + j0 + 1];
  }
  float cs0 = 0.f, cs1 = 0.f;
  int budget = 1 << 22;   // poll bailout (loud failure, bounded)

  for (int t = 0; t < 512; ++t){
    // x-part GEMM (independent of recurrence -> before the poll)
    f4 acc0 = {0,0,0,0}, acc1 = {0,0,0,0};
    const bf16* xr = xbf + ((size_t)(t*64 + mt*16 + lm)) * 256;
    #pragma unroll
    for (int kk = 0; kk < 8; ++kk){
      s8 A = ldg8(xr + kk*32 + q*8);
      acc0 = MFMA16(A, Bx[0][kk], acc0);
      acc1 = MFMA16(A, Bx[1][kk], acc1);
    }
    if (t > 0){
      const int* fp = flags + (size_t)(t-1)*32 + (lane & 31);
      while (budget > 0){
        int v;
        asm volatile("global_load_dword %0, %1, off sc0\n\ts_waitcnt vmcnt(0)"
                     : "=v"(v) : "v"(fp) : "memory");
        if (__ballot(v != 0) == ~0ull) break;
        budget--;
        __builtin_amdgcn_s_sleep(1);
      }
      // compiler reorder barrier only; no cache maintenance needed (same-XCD L2)
      __builtin_amdgcn_fence(__ATOMIC_ACQUIRE, "workgroup");
      const bf16* hr = lout + ((size_t)((t-1)*64 + mt*16 + lm)) * 512;
      #pragma unroll
      for (int kk = 0; kk < 16; ++kk){
        s8 Ah = ldg8(hr + kk*32 + q*8);
        acc0 = MFMA16(Ah, Bh[0][kk], acc0);
        acc1 = MFMA16(Ah, Bh[1][kk], acc1);
      }
    }
    // pre-activations -> LDS
    #pragma unroll
    for (int i = 0; i < 2; ++i){
      int col = (2*nh+i)*16 + lm;
      f4 av = (i == 0) ? acc0 : acc1;
      #pragma unroll
      for (int r = 0; r < 4; ++r) pre[mt*16 + q*4 + r][col] = av[r];
    }
    __syncthreads();
    // elementwise gates for 2 cells
    {
      float fh0 = pre[b0][ 0+j0] + bs[0], fh1 = pre[b0][ 0+j0+1] + bs[4];
      float ih0 = pre[b0][16+j0] + bs[1], ih1 = pre[b0][16+j0+1] + bs[5];
      float gh0 = pre[b0][32+j0] + bs[2], gh1 = pre[b0][32+j0+1] + bs[6];
      float oh0 = pre[b0][48+j0] + bs[3], oh1 = pre[b0][48+j0+1] + bs[7];
      cs0 = sigf(fh0)*cs0 + sigf(ih0)*tanhf_(gh0);
      cs1 = sigf(fh1)*cs1 + sigf(ih1)*tanhf_(gh1);
      float h0v = sigf(oh0)*tanhf_(cs0);
      float h1v = sigf(oh1)*tanhf_(cs1);
      unsigned hv = (unsigned)(unsigned short)f2bs(h0v) | ((unsigned)(unsigned short)f2bs(h1v) << 16);
      // plain store: write-through L1 -> lands in XCD0 L2 (the sync domain)
      *(unsigned*)(lout + ((size_t)(t*64 + b0))*512 + ns*16 + j0) = hv;
      if (t == 511){
        float* hx = out_tail + (size_t)b0*512 + ns*16 + j0;
        hx[0] = h0v; hx[1] = h1v;
        float* cx = out_tail + 32768 + (size_t)b0*512 + ns*16 + j0;
        cx[0] = cs0; cx[1] = cs1;
      }
    }
    __syncthreads();   // implies vmcnt(0): all h stores drained to L2
    if (tid == 0)
      *(volatile int*)(flags + (size_t)t*32 + ns) = 1;
  }
}

// ================= K2: fused QKV GEMM (N=1536), V written transposed =====
// grid (24, 512), 512 thr. Tile 64x64, K=512.
__global__ __launch_bounds__(512) void k2_qkv(const bf16* lout, const bf16* btqkv, const float* biasq,
                                              bf16* yq, bf16* yk, bf16* vt)
{
  int nb = blockIdx.x, rb = blockIdx.y;
  int tid = threadIdx.x, w = tid >> 6, lane = tid & 63;
  int mt = w >> 1, nh = w & 1, lm = lane & 15, q = lane >> 4;
  int row = rb*64 + mt*16 + lm;
  f4 acc[2] = {{0,0,0,0},{0,0,0,0}};
  const bf16* ap  = lout + (size_t)row * 512;
  const bf16* bp0 = btqkv + ((size_t)(nb*64 + (2*nh+0)*16 + lm)) * 512;
  const bf16* bp1 = btqkv + ((size_t)(nb*64 + (2*nh+1)*16 + lm)) * 512;
  #pragma unroll
  for (int kk = 0; kk < 16; ++kk){
    int kb = kk*32 + q*8;
    s8 A = ldg8(ap + kb);
    acc[0] = MFMA16(A, ldg8(bp0 + kb), acc[0]);
    acc[1] = MFMA16(A, ldg8(bp1 + kb), acc[1]);
  }
  #pragma unroll
  for (int i = 0; i < 2; ++i){
    int e = nb*64 + (2*nh+i)*16 + lm;
    float bias = biasq[e];
    #pragma unroll
    for (int r = 0; r < 4; ++r){
      int rr = rb*64 + mt*16 + q*4 + r;
      bf16 v = __float2bfloat16(acc[i][r] + bias);
      if (e < 512)        yq[(size_t)rr*512 + e] = v;
      else if (e < 1024)  yk[(size_t)rr*512 + (e-512)] = v;
      else {
        int d = e - 1024, hh = d >> 7, dh = d & 127;
        vt[((size_t)((rr >> 9)*4 + hh)*128 + dh)*512 + (rr & 511)] = v;
      }
    }
  }
}

// ================= K3: fused scores + softmax + PV -> decoded ============
// grid (8 rowblocks, 256 bh), 256 thr (4 waves, wave = 16-row Q tile).
// LDS: 64KiB union — sK[128][128] during scores, sP[64][512] (XOR-swizzled)
// for the P layout round-trip into the PV MFMA A-operand.
__global__ __launch_bounds__(256) void k3_attn(const bf16* yq, const bf16* yk, const bf16* vt,
                                               float* dec)
{
  int rb = blockIdx.x, bh = blockIdx.y;
  int b1 = bh >> 2, hh = bh & 3;
  int tid = threadIdx.x, w = tid >> 6, lane = tid & 63, lm = lane & 15, q = lane >> 4;
  __shared__ short sbuf[32768];             // 64KiB
  short (*sK)[128] = (short(*)[128])sbuf;   // 16384 shorts = 32KiB
  // A fragments (Q rows), K=128 -> 4 k-steps
  s8 Af[4];
  const bf16* apr = yq + ((size_t)(b1*512 + rb*64 + w*16 + lm))*512 + hh*128;
  #pragma unroll
  for (int kk = 0; kk < 4; ++kk) Af[kk] = ldg8(apr + kk*32 + q*8);
  f4 acc[32];
  #pragma unroll
  for (int nt = 0; nt < 32; ++nt) acc[nt] = (f4){0,0,0,0};

  for (int ch = 0; ch < 4; ++ch){
    __syncthreads();
    #pragma unroll
    for (int it = 0; it < 8; ++it){
      int lin = tid + it*256;              // 0..2047
      int srow = lin >> 4, seg = lin & 15; // 16 segs of 8 bf16
      int pseg = seg ^ (srow & 15);        // swizzle
      *(s8*)&sK[srow][pseg*8] =
        ldg8(yk + ((size_t)(b1*512 + ch*128 + srow))*512 + hh*128 + seg*8);
    }
    __syncthreads();
    #pragma unroll
    for (int ntl = 0; ntl < 8; ++ntl){
      int nt = ch*8 + ntl;
      int brow = ntl*16 + lm;
      #pragma unroll
      for (int kk = 0; kk < 4; ++kk){
        int c = (kk*4 + q) ^ lm;           // de-swizzle
        s8 Bfr = *(const s8*)&sK[brow][c*8];
        acc[nt] = MFMA16(Af[kk], Bfr, acc[nt]);
      }
    }
  }
  // softmax over the full 512-col row (16 lanes x 32 n-tiles)
  const float scale = 0.08838834764831845f;  // 1/sqrt(128)
  float mx[4], sm[4];
  #pragma unroll
  for (int r = 0; r < 4; ++r){
    float m = -1e30f;
    #pragma unroll
    for (int nt = 0; nt < 32; ++nt) m = fmaxf(m, acc[nt][r]);
    mx[r] = m;
  }
  #pragma unroll
  for (int d = 1; d < 16; d <<= 1){
    #pragma unroll
    for (int r = 0; r < 4; ++r) mx[r] = fmaxf(mx[r], __shfl_xor(mx[r], d, 64));
  }
  #pragma unroll
  for (int r = 0; r < 4; ++r){
    float s = 0.f;
    #pragma unroll
    for (int nt = 0; nt < 32; ++nt){
      float e = __expf(scale * (acc[nt][r] - mx[r]));
      acc[nt][r] = e; s += e;
    }
    sm[r] = s;
  }
  #pragma unroll
  for (int d = 1; d < 16; d <<= 1){
    #pragma unroll
    for (int r = 0; r < 4; ++r) sm[r] += __shfl_xor(sm[r], d, 64);
  }
  float inv[4];
  #pragma unroll
  for (int r = 0; r < 4; ++r) inv[r] = 1.f / sm[r];

  __syncthreads();   // all sK reads done before sP overwrites the buffer
  // P tile -> LDS, XOR-swizzled 16B chunks: phys = row*512 + ((col>>3)^(row&15))*8 + (col&7)
  #pragma unroll
  for (int nt = 0; nt < 32; ++nt){
    #pragma unroll
    for (int r = 0; r < 4; ++r){
      int rowp = w*16 + q*4 + r, col = nt*16 + lm;
      sbuf[rowp*512 + (((col >> 3) ^ (rowp & 15))*8) + (col & 7)] =
        f2bs(acc[nt][r] * inv[r]);
    }
  }
  // PV: wave-local (each wave reads only rows it wrote) — no barrier needed
  f4 o[8];
  #pragma unroll
  for (int n2 = 0; n2 < 8; ++n2) o[n2] = (f4){0,0,0,0};
  int rowa = w*16 + lm;
  #pragma unroll
  for (int kk = 0; kk < 16; ++kk){
    s8 A = *(const s8*)&sbuf[rowa*512 + (((kk*4 + q) ^ (rowa & 15))*8)];
    #pragma unroll
    for (int n2 = 0; n2 < 8; ++n2){
      s8 Bfr = ldg8(vt + ((size_t)(bh*128 + n2*16 + lm))*512 + kk*32 + q*8);
      o[n2] = MFMA16(A, Bfr, o[n2]);
    }
  }
  #pragma unroll
  for (int n2 = 0; n2 < 8; ++n2){
    int d = n2*16 + lm;
    #pragma unroll
    for (int r = 0; r < 4; ++r){
      int s1 = rb*64 + w*16 + q*4 + r;
      dec[((size_t)s1*64 + b1)*512 + hh*128 + d] = o[n2][r];
    }
  }
}

// ================= launcher =================
extern "C" void kernel_launch(void* const* d_in, const int* in_sizes, int n_in,
                              void* d_out, int out_size, void* d_ws, size_t ws_size,
                              hipStream_t stream)
{
  const float* x   = (const float*)d_in[0];
  const float* Wf  = (const float*)d_in[1];  const float* bfv = (const float*)d_in[2];
  const float* Wi  = (const float*)d_in[3];  const float* biv = (const float*)d_in[4];
  const float* Wg  = (const float*)d_in[5];  const float* bgv = (const float*)d_in[6];
  const float* Wo  = (const float*)d_in[7];  const float* bov = (const float*)d_in[8];
  const float* Wq  = (const float*)d_in[9];  const float* bqv = (const float*)d_in[10];
  const float* Wk  = (const float*)d_in[11]; const float* bkv = (const float*)d_in[12];
  const float* Wv  = (const float*)d_in[13]; const float* bvv = (const float*)d_in[14];

  char* ws = (char*)d_ws;
  int*   flags = (int*)  (ws + OF_FLAGS);
  float* bias4 = (float*)(ws + OF_BIAS4);
  float* biasq = (float*)(ws + OF_BIASQ);
  int*   claim = (int*)  (ws + OF_CLAIM);
  bf16*  btx   = (bf16*) (ws + OF_BTX);
  bf16*  bth   = (bf16*) (ws + OF_BTH);
  bf16*  btqkv = (bf16*) (ws + OF_BTQKV);
  bf16*  yq    = (bf16*) (ws + OF_YQ);
  bf16*  yk    = (bf16*) (ws + OF_YK);
  bf16*  vt    = (bf16*) (ws + OF_VT);

  char* outc = (char*)d_out;
  bf16*  lout = (bf16*)(outc + DOUT_LOUT);   // dead before decode writes
  bf16*  xbf  = (bf16*)(outc + DOUT_XBF);    // dead before decode writes
  float* out  = (float*)d_out;

  hipLaunchKernelGGL(k0_pack, dim3(2048), dim3(256), 0, stream,
                     x, Wf, Wi, Wg, Wo, bfv, biv, bgv, bov, Wq, Wk, Wv, bqv, bkv, bvv,
                     xbf, btx, bth, btqkv, bias4, biasq, flags, claim);
  hipLaunchKernelGGL(k1_lstm, dim3(512), dim3(512), 0, stream,
                     xbf, btx, bth, bias4, lout, flags, claim, out + DEC_SZ);
  hipLaunchKernelGGL(k2_qkv, dim3(24, 512), dim3(512), 0, stream, lout, btqkv, biasq, yq, yk, vt);
  hipLaunchKernelGGL(k3_attn, dim3(8, 256), dim3(256), 0, stream, yq, yk, vt, out);
}

// Round 9
// 4316.684 us; speedup vs baseline: 1.1831x; 1.0020x over previous
//
#include <hip/hip_runtime.h>
#include <hip/hip_bf16.h>

typedef __attribute__((ext_vector_type(8))) short s8;
typedef __attribute__((ext_vector_type(4))) float f4;

using bf16 = __hip_bfloat16;

#define MFMA16(a,b,c) __builtin_amdgcn_mfma_f32_16x16x32_bf16((a),(b),(c),0,0,0)

// HW_REG_XCC_ID (id=20), offset 0, width 4  ->  simm16 = id | (off<<6) | ((w-1)<<11)
#define GETREG_XCC_ID (20 | (0 << 6) | (3 << 11))

// ---------------- sizes ----------------
constexpr int SS = 512, BBATCH = 64, HIDN = 512;
constexpr size_t DEC_SZ = (size_t)SS * BBATCH * HIDN;  // 16777216 f32 = 64MiB

// ---------------- ws layout (bytes), total 101 MiB ----------------
constexpr size_t OF_FLAGS = 0;                  // 512*32*4 = 64KiB (one 128B line per step)
constexpr size_t OF_BIAS4 = 65536;              // 2048 f32
constexpr size_t OF_BIASQ = 73728;              // 1536 f32  (ends 79872)
constexpr size_t OF_CLAIM = 81920;              // int[0]=worker-slot counter
constexpr size_t OF_BTX   = 131072;             // Bt_x [2048][256] bf16 = 1MiB
constexpr size_t OF_BTH   = 1179648;            // Bt_h [2048][512] bf16 = 2MiB
constexpr size_t OF_BTQKV = 3276800;            // Bt_qkv [1536][512] bf16 = 1.5MiB
constexpr size_t OF_YQ    = (size_t)5  << 20;   // 32MiB
constexpr size_t OF_YK    = OF_YQ + ((size_t)32 << 20);
constexpr size_t OF_VT    = OF_YK + ((size_t)32 << 20);   // ends at 101MiB

// d_out scratch offsets (inside 64MiB decoded region; dead before decode writes)
constexpr size_t DOUT_LOUT = 0;                 // lout bf16 [32768][512] = 32MiB
constexpr size_t DOUT_XBF  = (size_t)32 << 20;  // xbf bf16 [32768][256] = 16MiB

// ---------------- helpers ----------------
__device__ inline s8 ldg8(const bf16* p){ return *(const s8*)p; }
__device__ inline short f2bs(float f){ return __builtin_bit_cast(short, __float2bfloat16(f)); }
__device__ inline float sigf(float x){ return 1.f/(1.f + __expf(-x)); }
__device__ inline float tanhf_(float x){ x = fminf(fmaxf(x, -15.f), 15.f); float e = __expf(2.f*x); return (e-1.f)/(e+1.f); }

// ================= K0: pack weights/biases/x, zero flags =================
__global__ void k0_pack(const float* x,
                        const float* Wf,const float* Wi,const float* Wg,const float* Wo,
                        const float* bfv,const float* biv,const float* bgv,const float* bov,
                        const float* Wq,const float* Wk,const float* Wv,
                        const float* bqv,const float* bkv,const float* bvv,
                        bf16* xbf, bf16* btx, bf16* bth, bf16* btqkv,
                        float* bias4, float* biasq, int* flags, int* claim)
{
  const float* WG[4] = {Wf, Wi, Wg, Wo};
  const float* BG[4] = {bfv, biv, bgv, bov};
  const float* WQ[3] = {Wq, Wk, Wv};
  const float* BQ[3] = {bqv, bkv, bvv};
  const long NX   = 8388608;   // 32768*256
  const long NBTH = 1048576;   // 2048*512
  const long NBTQ = 786432;    // 1536*512
  const long NBTX = 524288;    // 2048*256
  const long NF   = 16384;     // 512*32
  const long TOT  = NX + NBTH + NBTQ + NBTX + NF + 2048 + 1536 + 1;
  long stride = (long)gridDim.x * blockDim.x;
  for (long i = (long)blockIdx.x*blockDim.x + threadIdx.x; i < TOT; i += stride){
    if (i < NX){ xbf[i] = __float2bfloat16(x[i]); }
    else if (i < NX + NBTH){
      long j = i - NX; int n = (int)(j >> 9), k = (int)(j & 511);
      int g = n >> 9, hid = n & 511;
      bth[j] = __float2bfloat16(WG[g][(size_t)(256 + k)*512 + hid]);
    } else if (i < NX + NBTH + NBTQ){
      long j = i - NX - NBTH; int n = (int)(j >> 9), k = (int)(j & 511);
      int w = n >> 9, c = n & 511;
      btqkv[j] = __float2bfloat16(WQ[w][(size_t)k*512 + c]);
    } else if (i < NX + NBTH + NBTQ + NBTX){
      long j = i - NX - NBTH - NBTQ; int n = (int)(j >> 8), k = (int)(j & 255);
      int g = n >> 9, hid = n & 511;
      btx[j] = __float2bfloat16(WG[g][(size_t)k*512 + hid]);
    } else if (i < NX + NBTH + NBTQ + NBTX + NF){
      flags[i - NX - NBTH - NBTQ - NBTX] = 0;
    } else if (i < NX + NBTH + NBTQ + NBTX + NF + 2048){
      long j = i - NX - NBTH - NBTQ - NBTX - NF; int g = (int)(j >> 9), hid = (int)(j & 511);
      bias4[j] = BG[g][hid];
    } else if (i < NX + NBTH + NBTQ + NBTX + NF + 2048 + 1536){
      long j = i - NX - NBTH - NBTQ - NBTX - NF - 2048; int w = (int)(j >> 9), c = (int)(j & 511);
      biasq[j] = BQ[w][c];
    } else {
      claim[0] = 0;    // worker-slot counter
    }
  }
}

// ================= K1: persistent LSTM recurrence, XCD0-pinned ===========
// 512 blocks launched; first 32 blocks landing on XCD 0 claim worker slots;
// all others exit. All cross-block traffic stays inside XCD0's 4MiB L2.
//
// Round-9 theory: VGPR_Count=120 regardless of launch_bounds -> the
// compiler REMATERIALIZES the ~48 B-fragment + 24 A-fragment loads inside
// the step loop, pipelined only ~3 deep (r1 latency probe: +130cy/load
// exposed). 72 L2 loads / 3 in flight x 250cy ~= 6000cy/step of exposed
// VMEM latency — the invariant cost every protocol change missed.
// Fix (structural, not hints):
//   - weight B-fragments staged ONCE into LDS (sBh 64KB + sBx 32KB,
//     k3-proven XOR-seg swizzle kills the 1024B-stride bank conflict);
//     in-loop weight access becomes ds_read_b128 (~12cy, lgkm-pipelined).
//   - A-fragments batch-loaded into arrays (Ah[16] / Axf[8]) BEFORE the
//     MFMA chains -> all loads in flight -> ~one L2 latency per step.
//   - in-loop VMEM: 72 -> 24 loads/step.
// LDS total = 64K + 32K + pre 17.4K = ~113KB -> 1 block/CU.
__global__ __launch_bounds__(512, 2) void k1_lstm(const bf16* xbf, const bf16* btx, const bf16* bth,
                                                  const float* bias4, bf16* lout, int* flags,
                                                  int* claim, float* out_tail)
{
  __shared__ int s_ns;
  int xcc = (int)(__builtin_amdgcn_s_getreg(GETREG_XCC_ID) & 15);
  if (threadIdx.x == 0){
    int nsl = -1;
    if (xcc == 0){
      nsl = __hip_atomic_fetch_add(claim, 1, __ATOMIC_RELAXED, __HIP_MEMORY_SCOPE_AGENT);
      if (nsl >= 32) nsl = -1;
    }
    s_ns = nsl;
  }
  __syncthreads();
  int ns = s_ns;
  if (ns < 0) return;

  int tid = threadIdx.x, w = tid >> 6, lane = tid & 63;
  int mt = w >> 1, nh = w & 1, lm = lane & 15, q = lane >> 4;

  __shared__ short sBh[32768];    // [64 rows][64 segs of 8 bf16], swizzled: 64KB
  __shared__ short sBx[16384];    // [64 rows][32 segs of 8 bf16], swizzled: 32KB
  __shared__ float pre[64][68];   // 17.4KB

  // ---- stage weight slices into LDS (once) ----
  // sBh row r=g*16+rl  <-  bth row g*512 + ns*16 + rl (len 512), seg s -> s^rl
  #pragma unroll
  for (int i = 0; i < 8; ++i){
    int idx = tid + i*512;            // 0..4095 chunks of 8 bf16
    int r = idx >> 6, s = idx & 63;
    int g = r >> 4, rl = r & 15;
    *(s8*)&sBh[(r*64 + (s ^ rl))*8] =
      ldg8(bth + ((size_t)(g*512 + ns*16 + rl))*512 + s*8);
  }
  // sBx row r=g*16+rl  <-  btx row g*512 + ns*16 + rl (len 256), seg s -> s^rl
  #pragma unroll
  for (int i = 0; i < 4; ++i){
    int idx = tid + i*512;            // 0..2047
    int r = idx >> 5, s = idx & 31;
    int g = r >> 4, rl = r & 15;
    *(s8*)&sBx[(r*32 + (s ^ rl))*8] =
      ldg8(btx + ((size_t)(g*512 + ns*16 + rl))*256 + s*8);
  }

  // elementwise cells: thread owns (b0, j0) and (b0, j0+1)
  int c0 = 2*tid, b0 = c0 >> 4, j0 = c0 & 15;
  float bs[8];
  #pragma unroll
  for (int g = 0; g < 4; ++g){
    bs[g]   = bias4[g*512 + ns*16 + j0];
    bs[4+g] = bias4[g*512 + ns*16 + j0 + 1];
  }
  float cs0 = 0.f, cs1 = 0.f;
  int budget = 1 << 22;   // poll bailout (loud failure, bounded)
  int rb0 = (2*nh + 0)*16 + lm;   // local B row for gate 2nh
  int rb1 = (2*nh + 1)*16 + lm;   // local B row for gate 2nh+1

  __syncthreads();   // staged weights visible to all waves

  for (int t = 0; t < 512; ++t){
    // x-part GEMM: batch-load A fragments, B from LDS
    f4 acc0 = {0,0,0,0}, acc1 = {0,0,0,0};
    {
      const bf16* xr = xbf + ((size_t)(t*64 + mt*16 + lm)) * 256;
      s8 Axf[8];
      #pragma unroll
      for (int kk = 0; kk < 8; ++kk) Axf[kk] = ldg8(xr + kk*32 + q*8);
      #pragma unroll
      for (int kk = 0; kk < 8; ++kk){
        int c = (kk*4 + q) ^ lm;
        acc0 = MFMA16(Axf[kk], *(const s8*)&sBx[(rb0*32 + c)*8], acc0);
        acc1 = MFMA16(Axf[kk], *(const s8*)&sBx[(rb1*32 + c)*8], acc1);
      }
    }
    if (t > 0){
      const int* fp = flags + (size_t)(t-1)*32 + (lane & 31);
      while (budget > 0){
        int v;
        asm volatile("global_load_dword %0, %1, off sc0\n\ts_waitcnt vmcnt(0)"
                     : "=v"(v) : "v"(fp) : "memory");
        if (__ballot(v != 0) == ~0ull) break;
        budget--;
        __builtin_amdgcn_s_sleep(1);
      }
      // compiler reorder barrier only; no cache maintenance needed (same-XCD L2)
      __builtin_amdgcn_fence(__ATOMIC_ACQUIRE, "workgroup");
      const bf16* hr = lout + ((size_t)((t-1)*64 + mt*16 + lm)) * 512;
      s8 Ah[16];
      #pragma unroll
      for (int kk = 0; kk < 16; ++kk) Ah[kk] = ldg8(hr + kk*32 + q*8);
      #pragma unroll
      for (int kk = 0; kk < 16; ++kk){
        int c = (kk*4 + q) ^ lm;
        acc0 = MFMA16(Ah[kk], *(const s8*)&sBh[(rb0*64 + c)*8], acc0);
        acc1 = MFMA16(Ah[kk], *(const s8*)&sBh[(rb1*64 + c)*8], acc1);
      }
    }
    // pre-activations -> LDS
    #pragma unroll
    for (int i = 0; i < 2; ++i){
      int col = (2*nh+i)*16 + lm;
      f4 av = (i == 0) ? acc0 : acc1;
      #pragma unroll
      for (int r = 0; r < 4; ++r) pre[mt*16 + q*4 + r][col] = av[r];
    }
    __syncthreads();
    // elementwise gates for 2 cells
    {
      float fh0 = pre[b0][ 0+j0] + bs[0], fh1 = pre[b0][ 0+j0+1] + bs[4];
      float ih0 = pre[b0][16+j0] + bs[1], ih1 = pre[b0][16+j0+1] + bs[5];
      float gh0 = pre[b0][32+j0] + bs[2], gh1 = pre[b0][32+j0+1] + bs[6];
      float oh0 = pre[b0][48+j0] + bs[3], oh1 = pre[b0][48+j0+1] + bs[7];
      cs0 = sigf(fh0)*cs0 + sigf(ih0)*tanhf_(gh0);
      cs1 = sigf(fh1)*cs1 + sigf(ih1)*tanhf_(gh1);
      float h0v = sigf(oh0)*tanhf_(cs0);
      float h1v = sigf(oh1)*tanhf_(cs1);
      unsigned hv = (unsigned)(unsigned short)f2bs(h0v) | ((unsigned)(unsigned short)f2bs(h1v) << 16);
      // plain store: write-through L1 -> lands in XCD0 L2 (the sync domain)
      *(unsigned*)(lout + ((size_t)(t*64 + b0))*512 + ns*16 + j0) = hv;
      if (t == 511){
        float* hx = out_tail + (size_t)b0*512 + ns*16 + j0;
        hx[0] = h0v; hx[1] = h1v;
        float* cx = out_tail + 32768 + (size_t)b0*512 + ns*16 + j0;
        cx[0] = cs0; cx[1] = cs1;
      }
    }
    __syncthreads();   // implies vmcnt(0): all h stores drained to L2
    if (tid == 0)
      *(volatile int*)(flags + (size_t)t*32 + ns) = 1;
  }
}

// ================= K2: fused QKV GEMM (N=1536), V written transposed =====
// grid (24, 512), 512 thr. Tile 64x64, K=512.
__global__ __launch_bounds__(512) void k2_qkv(const bf16* lout, const bf16* btqkv, const float* biasq,
                                              bf16* yq, bf16* yk, bf16* vt)
{
  int nb = blockIdx.x, rb = blockIdx.y;
  int tid = threadIdx.x, w = tid >> 6, lane = tid & 63;
  int mt = w >> 1, nh = w & 1, lm = lane & 15, q = lane >> 4;
  int row = rb*64 + mt*16 + lm;
  f4 acc[2] = {{0,0,0,0},{0,0,0,0}};
  const bf16* ap  = lout + (size_t)row * 512;
  const bf16* bp0 = btqkv + ((size_t)(nb*64 + (2*nh+0)*16 + lm)) * 512;
  const bf16* bp1 = btqkv + ((size_t)(nb*64 + (2*nh+1)*16 + lm)) * 512;
  #pragma unroll
  for (int kk = 0; kk < 16; ++kk){
    int kb = kk*32 + q*8;
    s8 A = ldg8(ap + kb);
    acc[0] = MFMA16(A, ldg8(bp0 + kb), acc[0]);
    acc[1] = MFMA16(A, ldg8(bp1 + kb), acc[1]);
  }
  #pragma unroll
  for (int i = 0; i < 2; ++i){
    int e = nb*64 + (2*nh+i)*16 + lm;
    float bias = biasq[e];
    #pragma unroll
    for (int r = 0; r < 4; ++r){
      int rr = rb*64 + mt*16 + q*4 + r;
      bf16 v = __float2bfloat16(acc[i][r] + bias);
      if (e < 512)        yq[(size_t)rr*512 + e] = v;
      else if (e < 1024)  yk[(size_t)rr*512 + (e-512)] = v;
      else {
        int d = e - 1024, hh = d >> 7, dh = d & 127;
        vt[((size_t)((rr >> 9)*4 + hh)*128 + dh)*512 + (rr & 511)] = v;
      }
    }
  }
}

// ================= K3: fused scores + softmax + PV -> decoded ============
// grid (8 rowblocks, 256 bh), 256 thr (4 waves, wave = 16-row Q tile).
// LDS: 64KiB union — sK[128][128] during scores, sP[64][512] (XOR-swizzled)
// for the P layout round-trip into the PV MFMA A-operand.
__global__ __launch_bounds__(256) void k3_attn(const bf16* yq, const bf16* yk, const bf16* vt,
                                               float* dec)
{
  int rb = blockIdx.x, bh = blockIdx.y;
  int b1 = bh >> 2, hh = bh & 3;
  int tid = threadIdx.x, w = tid >> 6, lane = tid & 63, lm = lane & 15, q = lane >> 4;
  __shared__ short sbuf[32768];             // 64KiB
  short (*sK)[128] = (short(*)[128])sbuf;   // 16384 shorts = 32KiB
  // A fragments (Q rows), K=128 -> 4 k-steps
  s8 Af[4];
  const bf16* apr = yq + ((size_t)(b1*512 + rb*64 + w*16 + lm))*512 + hh*128;
  #pragma unroll
  for (int kk = 0; kk < 4; ++kk) Af[kk] = ldg8(apr + kk*32 + q*8);
  f4 acc[32];
  #pragma unroll
  for (int nt = 0; nt < 32; ++nt) acc[nt] = (f4){0,0,0,0};

  for (int ch = 0; ch < 4; ++ch){
    __syncthreads();
    #pragma unroll
    for (int it = 0; it < 8; ++it){
      int lin = tid + it*256;              // 0..2047
      int srow = lin >> 4, seg = lin & 15; // 16 segs of 8 bf16
      int pseg = seg ^ (srow & 15);        // swizzle
      *(s8*)&sK[srow][pseg*8] =
        ldg8(yk + ((size_t)(b1*512 + ch*128 + srow))*512 + hh*128 + seg*8);
    }
    __syncthreads();
    #pragma unroll
    for (int ntl = 0; ntl < 8; ++ntl){
      int nt = ch*8 + ntl;
      int brow = ntl*16 + lm;
      #pragma unroll
      for (int kk = 0; kk < 4; ++kk){
        int c = (kk*4 + q) ^ lm;           // de-swizzle
        s8 Bfr = *(const s8*)&sK[brow][c*8];
        acc[nt] = MFMA16(Af[kk], Bfr, acc[nt]);
      }
    }
  }
  // softmax over the full 512-col row (16 lanes x 32 n-tiles)
  const float scale = 0.08838834764831845f;  // 1/sqrt(128)
  float mx[4], sm[4];
  #pragma unroll
  for (int r = 0; r < 4; ++r){
    float m = -1e30f;
    #pragma unroll
    for (int nt = 0; nt < 32; ++nt) m = fmaxf(m, acc[nt][r]);
    mx[r] = m;
  }
  #pragma unroll
  for (int d = 1; d < 16; d <<= 1){
    #pragma unroll
    for (int r = 0; r < 4; ++r) mx[r] = fmaxf(mx[r], __shfl_xor(mx[r], d, 64));
  }
  #pragma unroll
  for (int r = 0; r < 4; ++r){
    float s = 0.f;
    #pragma unroll
    for (int nt = 0; nt < 32; ++nt){
      float e = __expf(scale * (acc[nt][r] - mx[r]));
      acc[nt][r] = e; s += e;
    }
    sm[r] = s;
  }
  #pragma unroll
  for (int d = 1; d < 16; d <<= 1){
    #pragma unroll
    for (int r = 0; r < 4; ++r) sm[r] += __shfl_xor(sm[r], d, 64);
  }
  float inv[4];
  #pragma unroll
  for (int r = 0; r < 4; ++r) inv[r] = 1.f / sm[r];

  __syncthreads();   // all sK reads done before sP overwrites the buffer
  // P tile -> LDS, XOR-swizzled 16B chunks: phys = row*512 + ((col>>3)^(row&15))*8 + (col&7)
  #pragma unroll
  for (int nt = 0; nt < 32; ++nt){
    #pragma unroll
    for (int r = 0; r < 4; ++r){
      int rowp = w*16 + q*4 + r, col = nt*16 + lm;
      sbuf[rowp*512 + (((col >> 3) ^ (rowp & 15))*8) + (col & 7)] =
        f2bs(acc[nt][r] * inv[r]);
    }
  }
  // PV: wave-local (each wave reads only rows it wrote) — no barrier needed
  f4 o[8];
  #pragma unroll
  for (int n2 = 0; n2 < 8; ++n2) o[n2] = (f4){0,0,0,0};
  int rowa = w*16 + lm;
  #pragma unroll
  for (int kk = 0; kk < 16; ++kk){
    s8 A = *(const s8*)&sbuf[rowa*512 + (((kk*4 + q) ^ (rowa & 15))*8)];
    #pragma unroll
    for (int n2 = 0; n2 < 8; ++n2){
      s8 Bfr = ldg8(vt + ((size_t)(bh*128 + n2*16 + lm))*512 + kk*32 + q*8);
      o[n2] = MFMA16(A, Bfr, o[n2]);
    }
  }
  #pragma unroll
  for (int n2 = 0; n2 < 8; ++n2){
    int d = n2*16 + lm;
    #pragma unroll
    for (int r = 0; r < 4; ++r){
      int s1 = rb*64 + w*16 + q*4 + r;
      dec[((size_t)s1*64 + b1)*512 + hh*128 + d] = o[n2][r];
    }
  }
}

// ================= launcher =================
extern "C" void kernel_launch(void* const* d_in, const int* in_sizes, int n_in,
                              void* d_out, int out_size, void* d_ws, size_t ws_size,
                              hipStream_t stream)
{
  const float* x   = (const float*)d_in[0];
  const float* Wf  = (const float*)d_in[1];  const float* bfv = (const float*)d_in[2];
  const float* Wi  = (const float*)d_in[3];  const float* biv = (const float*)d_in[4];
  const float* Wg  = (const float*)d_in[5];  const float* bgv = (const float*)d_in[6];
  const float* Wo  = (const float*)d_in[7];  const float* bov = (const float*)d_in[8];
  const float* Wq  = (const float*)d_in[9];  const float* bqv = (const float*)d_in[10];
  const float* Wk  = (const float*)d_in[11]; const float* bkv = (const float*)d_in[12];
  const float* Wv  = (const float*)d_in[13]; const float* bvv = (const float*)d_in[14];

  char* ws = (char*)d_ws;
  int*   flags = (int*)  (ws + OF_FLAGS);
  float* bias4 = (float*)(ws + OF_BIAS4);
  float* biasq = (float*)(ws + OF_BIASQ);
  int*   claim = (int*)  (ws + OF_CLAIM);
  bf16*  btx   = (bf16*) (ws + OF_BTX);
  bf16*  bth   = (bf16*) (ws + OF_BTH);
  bf16*  btqkv = (bf16*) (ws + OF_BTQKV);
  bf16*  yq    = (bf16*) (ws + OF_YQ);
  bf16*  yk    = (bf16*) (ws + OF_YK);
  bf16*  vt    = (bf16*) (ws + OF_VT);

  char* outc = (char*)d_out;
  bf16*  lout = (bf16*)(outc + DOUT_LOUT);   // dead before decode writes
  bf16*  xbf  = (bf16*)(outc + DOUT_XBF);    // dead before decode writes
  float* out  = (float*)d_out;

  hipLaunchKernelGGL(k0_pack, dim3(2048), dim3(256), 0, stream,
                     x, Wf, Wi, Wg, Wo, bfv, biv, bgv, bov, Wq, Wk, Wv, bqv, bkv, bvv,
                     xbf, btx, bth, btqkv, bias4, biasq, flags, claim);
  hipLaunchKernelGGL(k1_lstm, dim3(512), dim3(512), 0, stream,
                     xbf, btx, bth, bias4, lout, flags, claim, out + DEC_SZ);
  hipLaunchKernelGGL(k2_qkv, dim3(24, 512), dim3(512), 0, stream, lout, btqkv, biasq, yq, yk, vt);
  hipLaunchKernelGGL(k3_attn, dim3(8, 256), dim3(256), 0, stream, yq, yk, vt, out);
}